// Round 5
// baseline (829.468 us; speedup 1.0000x reference)
//
#include <hip/hip_runtime.h>
#include <hip/hip_bf16.h>
#include <hip/hip_fp16.h>
#include <math.h>

// GatedAttention R20: barrier-free flash_attn. R19 post-mortem: conflicts fixed
// (6.3M->2.1M) and pipeline reordered -- dur unchanged 145us. LDS 30%/MFMA 19%/
// VALU 21%/HBM 12%: nothing saturated => the 16-barrier Es round-trip structure
// itself is the wall. Fix: permuted-row QK (p = (row>>2)*8+(row&3)+4*sub over two
// 16-row subtiles) makes each lane own p=quad*8+{0..7} == PV B-frag k-layout, so
// E stays in-register (exp + cvt_pk, no LDS, no barriers). Wave owns a 32-p slice
// per 128-p tile; q-block 32 (ni=2), O partial[128c][32q] = 64 AGPR; 4-wave LDS
// reduce once at end. Q in 32 VGPR. launch_bounds(256,3). Rest = R15.

#define PI_F 3.1415926f

typedef __attribute__((ext_vector_type(8))) short short8;
typedef __attribute__((ext_vector_type(4))) float f32x4;
typedef _Float16 half8 __attribute__((ext_vector_type(8)));
typedef __attribute__((ext_vector_type(4))) unsigned short u16x4;
typedef unsigned short ushort_t;

__device__ __forceinline__ ushort_t f2bf(float x) {
    unsigned u = __float_as_uint(x);
    unsigned r = (u + 0x7FFFu + ((u >> 16) & 1u)) >> 16;
    return (ushort_t)r;
}
__device__ __forceinline__ void split16(float x, ushort_t& h, ushort_t& l) {
    __half hh = __float2half(x);
    h = __half_as_ushort(hh);
    l = __half_as_ushort(__float2half(x - __half2float(hh)));
}
__device__ __forceinline__ ushort_t f2h(float x) {
    return __half_as_ushort(__float2half(x));
}
__device__ __forceinline__ int swz(int r, int c) {
    return ((c ^ r ^ (r >> 2)) & 3) << 3;
}

// ---------------- weight transform: OIHW fp32 -> [ky*kx][oc][ic] fp16 hi/lo --------
__global__ __launch_bounds__(256) void transform_w_k(
    const float* __restrict__ w, ushort_t* __restrict__ Wh, ushort_t* __restrict__ Wl,
    int Cout, int Cin, int KK)
{
    int idx = blockIdx.x * 256 + threadIdx.x;
    int N = Cout * Cin * KK;
    if (idx >= N) return;
    int oc = idx / (Cin * KK);
    int rem = idx - oc * (Cin * KK);
    int ic = rem / KK;
    int t = rem - ic * KK;
    float v = w[idx];
    long dst = ((long)t * Cout + oc) * Cin + ic;
    split16(v, Wh[dst], Wl[dst]);
}

// ------- conv1 weight transform: [32][4][7][7] -> [7 ky][32 oc][32 k=kx*4+ic] ------
__global__ __launch_bounds__(256) void transform_w1_k(
    const float* __restrict__ w, ushort_t* __restrict__ Wh, ushort_t* __restrict__ Wl)
{
    int idx = blockIdx.x * 256 + threadIdx.x;
    if (idx >= 7 * 32 * 32) return;
    int ky = idx / 1024;
    int rem = idx - ky * 1024;
    int oc = rem >> 5;
    int k = rem & 31;
    float v = 0.f;
    if (k < 28) {
        int kx = k >> 2, ic = k & 3;
        v = w[((oc * 4 + ic) * 7 + ky) * 7 + kx];
    }
    split16(v, Wh[idx], Wl[idx]);
}

// ------- prep conv1 input: reflect-pad(3) -> channel-last [8][262][262][4] fp16 h --
__global__ __launch_bounds__(256) void prep_in_k(
    const float* __restrict__ imgs, const float* __restrict__ masks,
    ushort_t* __restrict__ Xh)
{
    const int iy = blockIdx.x, b = blockIdx.y;
    int sy = iy - 3; if (sy < 0) sy = -sy; if (sy >= 256) sy = 510 - sy;
    const int rb = sy << 8;
    const float* i0 = imgs + (long)b * 3 * 65536;
    const float* mk = masks + (long)b * 65536;
    for (int x = threadIdx.x; x < 262; x += 256) {
        int sx = x - 3; if (sx < 0) sx = -sx; if (sx >= 256) sx = 510 - sx;
        u16x4 hv;
        hv[0] = f2h(i0[rb + sx]);
        hv[1] = f2h(i0[65536 + rb + sx]);
        hv[2] = f2h(i0[131072 + rb + sx]);
        hv[3] = f2h(mk[rb + sx]);
        long o = ((long)(b * 262 + iy) * 262 + x) * 4;
        *(u16x4*)&Xh[o] = hv;
    }
}

// ------- conv1 MFMA (2-term): 32 oc x 64 px per block -----------
__global__ __launch_bounds__(256) void conv1_mfma_k(
    const ushort_t* __restrict__ Xinh,
    const ushort_t* __restrict__ W1h, const ushort_t* __restrict__ W1l,
    const float* __restrict__ bias, ushort_t* __restrict__ Oh)
{
    const int tid = threadIdx.x, lane = tid & 63, wid = tid >> 6;
    const int wm = wid & 1, wn = wid >> 1, l15 = lane & 15, quad = lane >> 4;
    const int ox0 = blockIdx.x * 64;
    const int oy = blockIdx.y, b = blockIdx.z;
    f32x4 acc[2];
    acc[0] = (f32x4){0.f, 0.f, 0.f, 0.f};
    acc[1] = (f32x4){0.f, 0.f, 0.f, 0.f};
#pragma unroll
    for (int ky = 0; ky < 7; ++ky) {
        long wo = (long)(ky * 32 + wm * 16 + l15) * 32 + quad * 8;
        half8 Ah = *(const half8*)&W1h[wo];
        half8 Al = *(const half8*)&W1l[wo];
        long xrow = ((long)(b * 262 + oy + ky) * 262 + ox0) * 4;
#pragma unroll
        for (int ni = 0; ni < 2; ++ni) {
            long xo = xrow + (wn * 32 + ni * 16 + l15) * 4 + quad * 8;
            half8 Bh = *(const half8*)&Xinh[xo];
            acc[ni] = __builtin_amdgcn_mfma_f32_16x16x32_f16(Ah, Bh, acc[ni], 0, 0, 0);
            acc[ni] = __builtin_amdgcn_mfma_f32_16x16x32_f16(Al, Bh, acc[ni], 0, 0, 0);
        }
    }
    const int ocf = wm * 16 + quad * 4;
    float4 bv = *(const float4*)&bias[ocf];
#pragma unroll
    for (int ni = 0; ni < 2; ++ni) {
        int n = ox0 + wn * 32 + ni * 16 + l15;
        u16x4 hv;
        hv[0] = f2h(fmaxf(acc[ni][0] + bv.x, 0.f));
        hv[1] = f2h(fmaxf(acc[ni][1] + bv.y, 0.f));
        hv[2] = f2h(fmaxf(acc[ni][2] + bv.z, 0.f));
        hv[3] = f2h(fmaxf(acc[ni][3] + bv.w, 0.f));
        long o = ((long)(b * 260 + oy + 2) * 260 + n + 2) * 32 + ocf;
        *(u16x4*)&Oh[o] = hv;
    }
}

// ------- pad-fill for channel-last reflect-padded h-only buffers ----
__global__ __launch_bounds__(256) void pad_cl_k(
    ushort_t* __restrict__ Xh, int Hp, int Wp, int PAD, int C, int H, int W)
{
    const int iy = blockIdx.x, b = blockIdx.y;
    int t = iy - PAD; if (t < 0) t = -t; if (t >= H) t = 2 * H - 2 - t;
    const int iys = t + PAD;
    const long rowd = ((long)(b * Hp + iy) * Wp) * C;
    const long rows = ((long)(b * Hp + iys) * Wp) * C;
    const int nch = Wp * (C >> 3);
    for (int idx = threadIdx.x; idx < nch; idx += 256) {
        int x = idx / (C >> 3);
        int cg = (idx - x * (C >> 3)) << 3;
        int t2 = x - PAD; if (t2 < 0) t2 = -t2; if (t2 >= W) t2 = 2 * W - 2 - t2;
        int xs = t2 + PAD;
        if (xs == x && iys == iy) continue;
        *(int4*)&Xh[rowd + (long)x * C + cg] = *(const int4*)&Xh[rows + (long)xs * C + cg];
    }
}

// ------- MFMA conv (2-term split), swizzled LDS, de-interleave for S=2 ----
template<int K, int S, int CIN, int CSTG, int MT, int NPX, bool WRITE_CL>
__global__ __launch_bounds__(256, 2) void conv_mfma_k(
    const ushort_t* __restrict__ Xh,
    const ushort_t* __restrict__ Wh, const ushort_t* __restrict__ Wl,
    const float* __restrict__ bias,
    int Hp, int Wp, int CoutT,
    ushort_t* __restrict__ Oh, int Hpn, int Wpn, int NP,
    float* __restrict__ Ofp)
{
    constexpr int WS = (NPX - 1) * S + K;
    constexpr int WS2 = (WS + 1) / 2;
    constexpr int MF = MT / 32;
    constexpr int NF = NPX / 32;
    __shared__ ushort_t Bsh[WS * CSTG];
    __shared__ ushort_t Ash[K * MT * CSTG];
    __shared__ ushort_t Asl[K * MT * CSTG];
    const int tid = threadIdx.x, lane = tid & 63, wid = tid >> 6;
    const int wm = wid & 1, wn = wid >> 1, l15 = lane & 15, quad = lane >> 4;
    const int bx = blockIdx.x, oy = blockIdx.y;
    const int NOC = CoutT / MT;
    const int ocg = blockIdx.z % NOC, b = blockIdx.z / NOC;
    const int ox0 = bx * NPX;

    f32x4 acc[MF][NF];
#pragma unroll
    for (int mi = 0; mi < MF; ++mi)
#pragma unroll
        for (int ni = 0; ni < NF; ++ni) acc[mi][ni] = (f32x4){0.f, 0.f, 0.f, 0.f};

#pragma unroll
    for (int ky = 0; ky < K; ++ky) {
        const long rowoff = ((long)(b * Hp + oy * S + ky) * Wp + ox0 * S) * CIN;
        for (int cs = 0; cs < CIN; cs += CSTG) {
            __syncthreads();
            constexpr int NCH = WS * CSTG / 8;
#pragma unroll
            for (int it = 0; it < (NCH + 255) / 256; ++it) {
                int flat = tid + it * 256;
                if (flat < NCH) {
                    int e0 = flat * 8;
                    int x = e0 / CSTG;
                    int cpos = (e0 - x * CSTG) >> 3;
                    int xs = (S == 1) ? x : ((x >> 1) + (x & 1) * WS2);
                    *(int4*)&Bsh[xs * CSTG + swz(xs, cpos)] =
                        *(const int4*)&Xh[rowoff + (long)x * CIN + cs + cpos * 8];
                }
            }
            constexpr int NW = K * MT * CSTG / 8;
#pragma unroll
            for (int it = 0; it < (NW + 255) / 256; ++it) {
                int flat = tid + it * 256;
                if (flat < NW) {
                    int e0 = flat * 8;
                    int kx = e0 / (MT * CSTG);
                    int rem = e0 - kx * MT * CSTG;
                    int oc = rem / CSTG;
                    int cpos = (rem - oc * CSTG) >> 3;
                    int arow = kx * MT + oc;
                    int dst = arow * CSTG + swz(arow, cpos);
                    long src = ((long)((ky * K + kx) * CoutT + ocg * MT + oc)) * CIN + cs + cpos * 8;
                    *(int4*)&Ash[dst] = *(const int4*)&Wh[src];
                    *(int4*)&Asl[dst] = *(const int4*)&Wl[src];
                }
            }
            __syncthreads();
#pragma unroll
            for (int kx = 0; kx < K; ++kx) {
                half8 Ah[MF], Al[MF], Bh[NF];
#pragma unroll
                for (int mi = 0; mi < MF; ++mi) {
                    int arow = kx * MT + wm * (MT / 2) + mi * 16 + l15;
                    int ao = arow * CSTG + swz(arow, quad);
                    Ah[mi] = *(const half8*)&Ash[ao];
                    Al[mi] = *(const half8*)&Asl[ao];
                }
#pragma unroll
                for (int ni = 0; ni < NF; ++ni) {
                    int m = wn * (NPX / 2) + ni * 16 + l15;
                    int xs = (S == 1) ? (m + kx) : (m + (kx >> 1) + (kx & 1) * WS2);
                    Bh[ni] = *(const half8*)&Bsh[xs * CSTG + swz(xs, quad)];
                }
#pragma unroll
                for (int mi = 0; mi < MF; ++mi)
#pragma unroll
                    for (int ni = 0; ni < NF; ++ni) {
                        acc[mi][ni] = __builtin_amdgcn_mfma_f32_16x16x32_f16(Ah[mi], Bh[ni], acc[mi][ni], 0, 0, 0);
                        acc[mi][ni] = __builtin_amdgcn_mfma_f32_16x16x32_f16(Al[mi], Bh[ni], acc[mi][ni], 0, 0, 0);
                    }
            }
        }
    }
#pragma unroll
    for (int ni = 0; ni < NF; ++ni) {
        const int n = ox0 + wn * (NPX / 2) + ni * 16 + l15;
#pragma unroll
        for (int mi = 0; mi < MF; ++mi) {
            const int ocf = ocg * MT + wm * (MT / 2) + mi * 16 + quad * 4;
            float4 bv = *(const float4*)&bias[ocf];
            float v0 = fmaxf(acc[mi][ni][0] + bv.x, 0.f);
            float v1 = fmaxf(acc[mi][ni][1] + bv.y, 0.f);
            float v2 = fmaxf(acc[mi][ni][2] + bv.z, 0.f);
            float v3 = fmaxf(acc[mi][ni][3] + bv.w, 0.f);
            if (WRITE_CL) {
                long o = ((long)(b * Hpn + oy + NP) * Wpn + n + NP) * CoutT + ocf;
                u16x4 hv;
                hv[0] = f2h(v0); hv[1] = f2h(v1); hv[2] = f2h(v2); hv[3] = f2h(v3);
                *(u16x4*)&Oh[o] = hv;
            } else {
                long o = ((long)(b * CoutT + ocf) << 12) + (oy << 6) + n;
                Ofp[o] = v0;
                Ofp[o + 4096] = v1;
                Ofp[o + 8192] = v2;
                Ofp[o + 12288] = v3;
            }
        }
    }
}

// -------- conv5 (256->1, K3 S1 P1) + relu + gate ----------
__global__ __launch_bounds__(256) void conv5_gate_k(
    const float* __restrict__ s4, const float* __restrict__ w,
    const float* __restrict__ bias, float* __restrict__ gate)
{
    const int tid = threadIdx.x;
    const int lane = tid & 63, g = tid >> 6;
    const int oy = blockIdx.x, b = blockIdx.y;
    int ixo[3], iyo[3];
#pragma unroll
    for (int k = 0; k < 3; ++k) {
        int ix = lane + k - 1; if (ix < 0) ix = -ix; if (ix >= 64) ix = 126 - ix;
        int iy = oy + k - 1; if (iy < 0) iy = -iy; if (iy >= 64) iy = 126 - iy;
        ixo[k] = ix; iyo[k] = iy << 6;
    }
    float part = 0.f;
    const float* inb = s4 + ((long)b * 256 + g * 64) * 4096;
    const float* wg = w + g * 64 * 9;
    for (int ic = 0; ic < 64; ++ic) {
        const float* inc = inb + ic * 4096;
        const float* wc = wg + ic * 9;
#pragma unroll
        for (int ky = 0; ky < 3; ++ky)
#pragma unroll
            for (int kx = 0; kx < 3; ++kx)
                part = fmaf(wc[ky * 3 + kx], inc[iyo[ky] + ixo[kx]], part);
    }
    __shared__ float red[4][64];
    red[g][lane] = part;
    __syncthreads();
    if (tid < 64) {
        float s = bias[0] + red[0][tid] + red[1][tid] + red[2][tid] + red[3][tid];
        s = fmaxf(s, 0.f);
        gate[(b << 12) + (oy << 6) + tid] = tanf(PI_F * (tanhf(s) - 0.5f));
    }
}

// ---------------- invn[b][p] = 1/sqrt(sum_c (F+1e-7)^2) ----------------
__global__ __launch_bounds__(256) void invn_k(const float* __restrict__ F, float* __restrict__ invn)
{
    const int p = blockIdx.x * 256 + threadIdx.x;
    const int b = blockIdx.y;
    const float* Fb = F + (long)b * 524288;
    float ss = 0.f;
#pragma unroll 8
    for (int c = 0; c < 128; ++c) {
        float v = Fb[c * 4096 + p] + 1e-7f;
        ss = fmaf(v, v, ss);
    }
    invn[(b << 12) + p] = 1.0f / sqrtf(ss);
}

// -------- prep: Fo16[b][c][p] = bf16(F), Ft16[b][p][c] = bf16(F^T) ---------------
__global__ __launch_bounds__(256) void prep_bf16_k(
    const float* __restrict__ F, ushort_t* __restrict__ Fo16, ushort_t* __restrict__ Ft16)
{
    __shared__ float Ls[128][65];
    const int tid = threadIdx.x;
    const int lane = tid & 63, wv = tid >> 6;
    const int p0 = blockIdx.x * 64, b = blockIdx.y;
#pragma unroll 8
    for (int cc = 0; cc < 32; ++cc) {
        int c = wv * 32 + cc;
        long idx = ((long)b * 128 + c) * 4096 + p0 + lane;
        float v = F[idx];
        Fo16[idx] = f2bf(v);
        Ls[c][lane] = v;
    }
    __syncthreads();
#pragma unroll 8
    for (int i = 0; i < 32; ++i) {
        int flat = tid + 256 * i;
        int c = flat & 127, pl_ = flat >> 7;
        Ft16[((long)b * 4096 + p0 + pl_) * 128 + c] = f2bf(Ls[c][pl_]);
    }
}

// -------- flash attention (R20): barrier-free, E in-register via permuted-row QK.
// Block = 32 q x 1024 p x 128 c; 4 waves each own a 32-p slice per 128-p tile.
// QK subtile sub: A-row r loads Ft row p0w + (r>>2)*8 + (r&3) + 4*sub, so lane
// (quad,l15) ends up with S for p = quad*8+{0..7} == PV B-frag k-layout.
// exp -> cvt_pk -> PV mfma directly; partial O[2 ni][8 ct] (64 AGPR); one LDS
// reduce at the end. Zero main-loop barriers, zero Es/Qs traffic. ------------------
__global__ __launch_bounds__(256, 3) void flash_attn_k(
    const ushort_t* __restrict__ Ft16, const ushort_t* __restrict__ Fo16,
    const float* __restrict__ invn, const float* __restrict__ gate,
    float* __restrict__ Opart, float* __restrict__ lpart)
{
    __shared__ float redS[32][4];
    __shared__ float Ored[32 * 132];
    const int tid = threadIdx.x, lane = tid & 63, w = tid >> 6;
    const int l15 = lane & 15, quad = lane >> 4;
    const int q0 = blockIdx.x * 32;
    const int ks = blockIdx.y, b = blockIdx.z;
    const int bp = b << 12;
    const ushort_t* Ftb = Ft16 + (long)b * 4096 * 128;
    const ushort_t* Fob = Fo16 + (long)b * 128 * 4096;

    // Q fragments in registers (ni=0..1, cs=0..3): B[k=c][col=q]
    short8 Bq[2][4];
#pragma unroll
    for (int ni = 0; ni < 2; ++ni)
#pragma unroll
        for (int cs = 0; cs < 4; ++cs)
            Bq[ni][cs] = *(const short8*)&Ftb[(long)(q0 + ni * 16 + l15) * 128 + cs * 32 + quad * 8];

    f32x4 O[2][8];
#pragma unroll
    for (int ni = 0; ni < 2; ++ni)
#pragma unroll
        for (int ct = 0; ct < 8; ++ct) O[ni][ct] = (f32x4){0.f, 0.f, 0.f, 0.f};
    float l_acc[2] = {0.f, 0.f};

    union BeU { short8 v; __hip_bfloat162 h[4]; };
    const int p_beg = ks * 1024;
    const int prow_base = ((l15 & 12) << 1) + (l15 & 3);  // (row>>2)*8 + (row&3)

    for (int t = 0; t < 8; ++t) {
        const int p0w = p_beg + t * 128 + w * 32;
        BeU be0, be1;
#pragma unroll
        for (int sub = 0; sub < 2; ++sub) {
            const long prow = p0w + prow_base + sub * 4;
            f32x4 Sa[2];
            Sa[0] = (f32x4){0.f, 0.f, 0.f, 0.f};
            Sa[1] = (f32x4){0.f, 0.f, 0.f, 0.f};
#pragma unroll
            for (int cs = 0; cs < 4; ++cs) {
                short8 Ap = *(const short8*)&Ftb[prow * 128 + cs * 32 + quad * 8];
                Sa[0] = __builtin_amdgcn_mfma_f32_16x16x32_bf16(Ap, Bq[0][cs], Sa[0], 0, 0, 0);
                Sa[1] = __builtin_amdgcn_mfma_f32_16x16x32_bf16(Ap, Bq[1][cs], Sa[1], 0, 0, 0);
            }
            // lane (quad,l15) now holds S[p = p0w + quad*8 + sub*4 + r][q = q0+ni*16+l15]
            float4 iv = *(const float4*)&invn[bp + p0w + quad * 8 + sub * 4];
            float4 gt = *(const float4*)&gate[bp + p0w + quad * 8 + sub * 4];
#pragma unroll
            for (int ni = 0; ni < 2; ++ni) {
                float e0 = __expf(fmaf(Sa[ni][0], iv.x, gt.x));
                float e1 = __expf(fmaf(Sa[ni][1], iv.y, gt.y));
                float e2 = __expf(fmaf(Sa[ni][2], iv.z, gt.z));
                float e3 = __expf(fmaf(Sa[ni][3], iv.w, gt.w));
                BeU& be = (ni == 0) ? be0 : be1;
                be.h[sub * 2]     = __float22bfloat162_rn(make_float2(e0, e1));
                be.h[sub * 2 + 1] = __float22bfloat162_rn(make_float2(e2, e3));
                l_acc[ni] += (e0 + e1) + (e2 + e3);
            }
        }
        // PV: A = V fragment (row=c, k=p), B = in-register E
#pragma unroll
        for (int ct = 0; ct < 8; ++ct) {
            short8 Va = *(const short8*)&Fob[(long)(ct * 16 + l15) * 4096 + p0w + quad * 8];
            O[0][ct] = __builtin_amdgcn_mfma_f32_16x16x32_bf16(Va, be0.v, O[0][ct], 0, 0, 0);
            O[1][ct] = __builtin_amdgcn_mfma_f32_16x16x32_bf16(Va, be1.v, O[1][ct], 0, 0, 0);
        }
    }

    // ---- lpart partial: sum over this wave's p-set, reduce over quads ----
#pragma unroll
    for (int ni = 0; ni < 2; ++ni) {
        float lt = l_acc[ni];
        lt += __shfl_xor(lt, 16);
        lt += __shfl_xor(lt, 32);
        if (quad == 0) redS[ni * 16 + l15][w] = lt;
    }
    __syncthreads();

    // ---- 4-wave sequential O reduce into Ored[q][c] (stride 132) ----
#pragma unroll
    for (int rw = 0; rw < 4; ++rw) {
        if (w == rw) {
#pragma unroll
            for (int ni = 0; ni < 2; ++ni)
#pragma unroll
                for (int ct = 0; ct < 8; ++ct) {
                    float* dst = &Ored[(ni * 16 + l15) * 132 + ct * 16 + quad * 4];
                    if (rw == 0) {
                        *(float4*)dst = make_float4(O[ni][ct][0], O[ni][ct][1], O[ni][ct][2], O[ni][ct][3]);
                    } else {
                        float4 v = *(const float4*)dst;
                        v.x += O[ni][ct][0]; v.y += O[ni][ct][1];
                        v.z += O[ni][ct][2]; v.w += O[ni][ct][3];
                        *(float4*)dst = v;
                    }
                }
        }
        __syncthreads();
    }

    if (tid < 32) {
        float4 rs = *(const float4*)&redS[tid][0];
        lpart[(ks * 8 + b) * 4096 + q0 + tid] = (rs.x + rs.y) + (rs.z + rs.w);
    }
    // ---- cooperative coalesced Opart write: lane-adjacent q ----
    float* Ob = Opart + (long)(ks * 8 + b) * 524288;
    const int qw = tid & 31, cg = (tid >> 5) * 16;
#pragma unroll
    for (int j = 0; j < 16; ++j)
        Ob[((long)(cg + j) << 12) + q0 + qw] = Ored[qw * 132 + cg + j];
}

// ---------------- combiner: merge 4 split-K partials ----------------
__global__ __launch_bounds__(256) void combiner_k(
    const float* __restrict__ Opart, const float* __restrict__ lpart,
    const float* __restrict__ F, const float* __restrict__ cw,
    const float* __restrict__ cb, float* __restrict__ out)
{
    const int tid = threadIdx.x;
    const int q = blockIdx.x * 256 + tid;
    const int o0 = blockIdx.y << 4;
    const int b = blockIdx.z;
    float lsum = 0.f;
#pragma unroll
    for (int ks = 0; ks < 4; ++ks) lsum += lpart[(ks * 8 + b) * 4096 + q];
    float il = 1.0f / lsum;
    const float* Fb = F + (long)b * 524288 + q;
    float acc[16];
#pragma unroll
    for (int j = 0; j < 16; ++j) acc[j] = cb[o0 + j];
    for (int c = 0; c < 128; ++c) {
        float a = 0.f;
#pragma unroll
        for (int ks = 0; ks < 4; ++ks)
            a += Opart[(long)(ks * 8 + b) * 524288 + (long)c * 4096 + q];
        a *= il;
        float f = Fb[(long)c * 4096];
#pragma unroll
        for (int j = 0; j < 16; ++j) {
            acc[j] = fmaf(cw[(o0 + j) * 256 + c], a, acc[j]);
            acc[j] = fmaf(cw[(o0 + j) * 256 + 128 + c], f, acc[j]);
        }
    }
#pragma unroll
    for (int j = 0; j < 16; ++j)
        out[((long)(b * 128 + o0 + j) << 12) + q] = acc[j];
}

// =====================================================================================
extern "C" void kernel_launch(void* const* d_in, const int* in_sizes, int n_in,
                              void* d_out, int out_size, void* d_ws, size_t ws_size,
                              hipStream_t stream)
{
    const float* F     = (const float*)d_in[0];
    const float* imgs  = (const float*)d_in[1];
    const float* masks = (const float*)d_in[2];
    const float* gw1 = (const float*)d_in[3];  const float* gb1 = (const float*)d_in[4];
    const float* gw2 = (const float*)d_in[5];  const float* gb2 = (const float*)d_in[6];
    const float* gw3 = (const float*)d_in[7];  const float* gb3 = (const float*)d_in[8];
    const float* gw4 = (const float*)d_in[9];  const float* gb4 = (const float*)d_in[10];
    const float* gw5 = (const float*)d_in[11]; const float* gb5 = (const float*)d_in[12];
    const float* cw  = (const float*)d_in[13]; const float* cb  = (const float*)d_in[14];
    float* out = (float*)d_out;

    // ---- workspace layout (float offsets), ~150 MB ----
    float* W = (float*)d_ws;
    ushort_t* Xcl2h = (ushort_t*)(W);                 // [8][260][260][32] fp16 h
    ushort_t* Xcl4h = (ushort_t*)(W);                 // [8][130][130][128] fp16 h
    float*    Opart = W;                              // [4][8][128][4096] f32
    float*    lpart = W + 16777216;                   // [4][8][4096]
    ushort_t* Xcl3h = (ushort_t*)(W + 17305600);      // [8][132][132][64] fp16 h
    ushort_t* Fo16  = (ushort_t*)(W + 17305600);      // [8][128][4096] bf16 (after conv3)
    float*    s4   = W + 26226688;                    // [8][256][64][64] f32
    ushort_t* Ft16 = (ushort_t*)(W + 30420992);       // [8][4096][128] bf16 (after conv5)
    ushort_t* W2h = (ushort_t*)(W + 34615296);
    ushort_t* W2l = (ushort_t*)(W + 34640896);
    ushort_t* W3h = (ushort_t*)(W + 34666496);
    ushort_t* W3l = (ushort_t*)(W + 34768896);
    ushort_t* W4h = (ushort_t*)(W + 34871296);
    ushort_t* W4l = (ushort_t*)(W + 35018752);
    float* gate = W + 35166208;
    float* invn = W + 35198976;
    ushort_t* Xinh = (ushort_t*)(W + 35231744);       // [8][262][262][4] fp16 h + slack
    ushort_t* W1h  = (ushort_t*)(W + 37428416);       // [7][32][32] fp16
    ushort_t* W1l  = (ushort_t*)(W + 37432000);

    // ---- weight transforms + conv1 input prep ----
    transform_w_k<<<dim3(200),  256, 0, stream>>>(gw2, W2h, W2l, 64, 32, 25);
    transform_w_k<<<dim3(800),  256, 0, stream>>>(gw3, W3h, W3l, 128, 64, 25);
    transform_w_k<<<dim3(1152), 256, 0, stream>>>(gw4, W4h, W4l, 256, 128, 9);
    transform_w1_k<<<dim3(28), 256, 0, stream>>>(gw1, W1h, W1l);
    prep_in_k<<<dim3(262, 8), 256, 0, stream>>>(imgs, masks, Xinh);

    // ---- conv stack (2-term split: weights h+l, activations h only) ----
    conv1_mfma_k<<<dim3(4, 256, 8), 256, 0, stream>>>(Xinh, W1h, W1l, gb1, Xcl2h);
    pad_cl_k<<<dim3(260, 8), 256, 0, stream>>>(Xcl2h, 260, 260, 2, 32, 256, 256);
    conv_mfma_k<5, 2, 32, 32, 64, 128, true><<<dim3(1, 128, 8), 256, 0, stream>>>(
        Xcl2h, W2h, W2l, gb2, 260, 260, 64, Xcl3h, 132, 132, 2, nullptr);
    pad_cl_k<<<dim3(132, 8), 256, 0, stream>>>(Xcl3h, 132, 132, 2, 64, 128, 128);
    conv_mfma_k<5, 1, 64, 32, 64, 128, true><<<dim3(1, 128, 16), 256, 0, stream>>>(
        Xcl3h, W3h, W3l, gb3, 132, 132, 128, Xcl4h, 130, 130, 1, nullptr);
    pad_cl_k<<<dim3(130, 8), 256, 0, stream>>>(Xcl4h, 130, 130, 1, 128, 128, 128);
    conv_mfma_k<3, 2, 128, 32, 128, 64, false><<<dim3(1, 64, 16), 256, 0, stream>>>(
        Xcl4h, W4h, W4l, gb4, 130, 130, 256, nullptr, 0, 0, 0, s4);
    conv5_gate_k<<<dim3(64, 8), 256, 0, stream>>>(s4, gw5, gb5, gate);

    // ---- attention ----
    invn_k<<<dim3(16, 8), 256, 0, stream>>>(F, invn);
    prep_bf16_k<<<dim3(64, 8), 256, 0, stream>>>(F, Fo16, Ft16);
    flash_attn_k<<<dim3(128, 4, 8), 256, 0, stream>>>(Ft16, Fo16, invn, gate, Opart, lpart);
    combiner_k<<<dim3(16, 8, 8), 256, 0, stream>>>(Opart, lpart, F, cw, cb, out);
}

// Round 6
// 649.766 us; speedup vs baseline: 1.2766x; 1.2766x over previous
//
#include <hip/hip_runtime.h>
#include <hip/hip_bf16.h>
#include <hip/hip_fp16.h>
#include <math.h>

// GatedAttention R21: revert R20 (q=32 in-register-E: 2x stream traffic + 4x write
// amplification, 339us). Back to R19 structure (145us: frag-ordered Es, pipelined
// loop) + the one proven lever: occupancy. 4->5 blocks/CU: launch_bounds(256,5)
// (reg cap 102; usage 92+8=100), Qs 16->14 frags in LDS (frags 14,15 = ni3/cs2,3
// in regs, +8), LDS 33792->31744 <= 32768 -> 5 blocks/CU = 62.5% steady occupancy.
// Conv stack/combiner = R15.

#define PI_F 3.1415926f

typedef __attribute__((ext_vector_type(8))) short short8;
typedef __attribute__((ext_vector_type(4))) float f32x4;
typedef _Float16 half8 __attribute__((ext_vector_type(8)));
typedef __attribute__((ext_vector_type(4))) unsigned short u16x4;
typedef unsigned short ushort_t;

__device__ __forceinline__ ushort_t f2bf(float x) {
    unsigned u = __float_as_uint(x);
    unsigned r = (u + 0x7FFFu + ((u >> 16) & 1u)) >> 16;
    return (ushort_t)r;
}
__device__ __forceinline__ void split16(float x, ushort_t& h, ushort_t& l) {
    __half hh = __float2half(x);
    h = __half_as_ushort(hh);
    l = __half_as_ushort(__float2half(x - __half2float(hh)));
}
__device__ __forceinline__ ushort_t f2h(float x) {
    return __half_as_ushort(__float2half(x));
}
__device__ __forceinline__ int swz(int r, int c) {
    return ((c ^ r ^ (r >> 2)) & 3) << 3;
}

// ---------------- weight transform: OIHW fp32 -> [ky*kx][oc][ic] fp16 hi/lo --------
__global__ __launch_bounds__(256) void transform_w_k(
    const float* __restrict__ w, ushort_t* __restrict__ Wh, ushort_t* __restrict__ Wl,
    int Cout, int Cin, int KK)
{
    int idx = blockIdx.x * 256 + threadIdx.x;
    int N = Cout * Cin * KK;
    if (idx >= N) return;
    int oc = idx / (Cin * KK);
    int rem = idx - oc * (Cin * KK);
    int ic = rem / KK;
    int t = rem - ic * KK;
    float v = w[idx];
    long dst = ((long)t * Cout + oc) * Cin + ic;
    split16(v, Wh[dst], Wl[dst]);
}

// ------- conv1 weight transform: [32][4][7][7] -> [7 ky][32 oc][32 k=kx*4+ic] ------
__global__ __launch_bounds__(256) void transform_w1_k(
    const float* __restrict__ w, ushort_t* __restrict__ Wh, ushort_t* __restrict__ Wl)
{
    int idx = blockIdx.x * 256 + threadIdx.x;
    if (idx >= 7 * 32 * 32) return;
    int ky = idx / 1024;
    int rem = idx - ky * 1024;
    int oc = rem >> 5;
    int k = rem & 31;
    float v = 0.f;
    if (k < 28) {
        int kx = k >> 2, ic = k & 3;
        v = w[((oc * 4 + ic) * 7 + ky) * 7 + kx];
    }
    split16(v, Wh[idx], Wl[idx]);
}

// ------- prep conv1 input: reflect-pad(3) -> channel-last [8][262][262][4] fp16 h --
__global__ __launch_bounds__(256) void prep_in_k(
    const float* __restrict__ imgs, const float* __restrict__ masks,
    ushort_t* __restrict__ Xh)
{
    const int iy = blockIdx.x, b = blockIdx.y;
    int sy = iy - 3; if (sy < 0) sy = -sy; if (sy >= 256) sy = 510 - sy;
    const int rb = sy << 8;
    const float* i0 = imgs + (long)b * 3 * 65536;
    const float* mk = masks + (long)b * 65536;
    for (int x = threadIdx.x; x < 262; x += 256) {
        int sx = x - 3; if (sx < 0) sx = -sx; if (sx >= 256) sx = 510 - sx;
        u16x4 hv;
        hv[0] = f2h(i0[rb + sx]);
        hv[1] = f2h(i0[65536 + rb + sx]);
        hv[2] = f2h(i0[131072 + rb + sx]);
        hv[3] = f2h(mk[rb + sx]);
        long o = ((long)(b * 262 + iy) * 262 + x) * 4;
        *(u16x4*)&Xh[o] = hv;
    }
}

// ------- conv1 MFMA (2-term): 32 oc x 64 px per block -----------
__global__ __launch_bounds__(256) void conv1_mfma_k(
    const ushort_t* __restrict__ Xinh,
    const ushort_t* __restrict__ W1h, const ushort_t* __restrict__ W1l,
    const float* __restrict__ bias, ushort_t* __restrict__ Oh)
{
    const int tid = threadIdx.x, lane = tid & 63, wid = tid >> 6;
    const int wm = wid & 1, wn = wid >> 1, l15 = lane & 15, quad = lane >> 4;
    const int ox0 = blockIdx.x * 64;
    const int oy = blockIdx.y, b = blockIdx.z;
    f32x4 acc[2];
    acc[0] = (f32x4){0.f, 0.f, 0.f, 0.f};
    acc[1] = (f32x4){0.f, 0.f, 0.f, 0.f};
#pragma unroll
    for (int ky = 0; ky < 7; ++ky) {
        long wo = (long)(ky * 32 + wm * 16 + l15) * 32 + quad * 8;
        half8 Ah = *(const half8*)&W1h[wo];
        half8 Al = *(const half8*)&W1l[wo];
        long xrow = ((long)(b * 262 + oy + ky) * 262 + ox0) * 4;
#pragma unroll
        for (int ni = 0; ni < 2; ++ni) {
            long xo = xrow + (wn * 32 + ni * 16 + l15) * 4 + quad * 8;
            half8 Bh = *(const half8*)&Xinh[xo];
            acc[ni] = __builtin_amdgcn_mfma_f32_16x16x32_f16(Ah, Bh, acc[ni], 0, 0, 0);
            acc[ni] = __builtin_amdgcn_mfma_f32_16x16x32_f16(Al, Bh, acc[ni], 0, 0, 0);
        }
    }
    const int ocf = wm * 16 + quad * 4;
    float4 bv = *(const float4*)&bias[ocf];
#pragma unroll
    for (int ni = 0; ni < 2; ++ni) {
        int n = ox0 + wn * 32 + ni * 16 + l15;
        u16x4 hv;
        hv[0] = f2h(fmaxf(acc[ni][0] + bv.x, 0.f));
        hv[1] = f2h(fmaxf(acc[ni][1] + bv.y, 0.f));
        hv[2] = f2h(fmaxf(acc[ni][2] + bv.z, 0.f));
        hv[3] = f2h(fmaxf(acc[ni][3] + bv.w, 0.f));
        long o = ((long)(b * 260 + oy + 2) * 260 + n + 2) * 32 + ocf;
        *(u16x4*)&Oh[o] = hv;
    }
}

// ------- pad-fill for channel-last reflect-padded h-only buffers ----
__global__ __launch_bounds__(256) void pad_cl_k(
    ushort_t* __restrict__ Xh, int Hp, int Wp, int PAD, int C, int H, int W)
{
    const int iy = blockIdx.x, b = blockIdx.y;
    int t = iy - PAD; if (t < 0) t = -t; if (t >= H) t = 2 * H - 2 - t;
    const int iys = t + PAD;
    const long rowd = ((long)(b * Hp + iy) * Wp) * C;
    const long rows = ((long)(b * Hp + iys) * Wp) * C;
    const int nch = Wp * (C >> 3);
    for (int idx = threadIdx.x; idx < nch; idx += 256) {
        int x = idx / (C >> 3);
        int cg = (idx - x * (C >> 3)) << 3;
        int t2 = x - PAD; if (t2 < 0) t2 = -t2; if (t2 >= W) t2 = 2 * W - 2 - t2;
        int xs = t2 + PAD;
        if (xs == x && iys == iy) continue;
        *(int4*)&Xh[rowd + (long)x * C + cg] = *(const int4*)&Xh[rows + (long)xs * C + cg];
    }
}

// ------- MFMA conv (2-term split), swizzled LDS, de-interleave for S=2 ----
template<int K, int S, int CIN, int CSTG, int MT, int NPX, bool WRITE_CL>
__global__ __launch_bounds__(256, 2) void conv_mfma_k(
    const ushort_t* __restrict__ Xh,
    const ushort_t* __restrict__ Wh, const ushort_t* __restrict__ Wl,
    const float* __restrict__ bias,
    int Hp, int Wp, int CoutT,
    ushort_t* __restrict__ Oh, int Hpn, int Wpn, int NP,
    float* __restrict__ Ofp)
{
    constexpr int WS = (NPX - 1) * S + K;
    constexpr int WS2 = (WS + 1) / 2;
    constexpr int MF = MT / 32;
    constexpr int NF = NPX / 32;
    __shared__ ushort_t Bsh[WS * CSTG];
    __shared__ ushort_t Ash[K * MT * CSTG];
    __shared__ ushort_t Asl[K * MT * CSTG];
    const int tid = threadIdx.x, lane = tid & 63, wid = tid >> 6;
    const int wm = wid & 1, wn = wid >> 1, l15 = lane & 15, quad = lane >> 4;
    const int bx = blockIdx.x, oy = blockIdx.y;
    const int NOC = CoutT / MT;
    const int ocg = blockIdx.z % NOC, b = blockIdx.z / NOC;
    const int ox0 = bx * NPX;

    f32x4 acc[MF][NF];
#pragma unroll
    for (int mi = 0; mi < MF; ++mi)
#pragma unroll
        for (int ni = 0; ni < NF; ++ni) acc[mi][ni] = (f32x4){0.f, 0.f, 0.f, 0.f};

#pragma unroll
    for (int ky = 0; ky < K; ++ky) {
        const long rowoff = ((long)(b * Hp + oy * S + ky) * Wp + ox0 * S) * CIN;
        for (int cs = 0; cs < CIN; cs += CSTG) {
            __syncthreads();
            constexpr int NCH = WS * CSTG / 8;
#pragma unroll
            for (int it = 0; it < (NCH + 255) / 256; ++it) {
                int flat = tid + it * 256;
                if (flat < NCH) {
                    int e0 = flat * 8;
                    int x = e0 / CSTG;
                    int cpos = (e0 - x * CSTG) >> 3;
                    int xs = (S == 1) ? x : ((x >> 1) + (x & 1) * WS2);
                    *(int4*)&Bsh[xs * CSTG + swz(xs, cpos)] =
                        *(const int4*)&Xh[rowoff + (long)x * CIN + cs + cpos * 8];
                }
            }
            constexpr int NW = K * MT * CSTG / 8;
#pragma unroll
            for (int it = 0; it < (NW + 255) / 256; ++it) {
                int flat = tid + it * 256;
                if (flat < NW) {
                    int e0 = flat * 8;
                    int kx = e0 / (MT * CSTG);
                    int rem = e0 - kx * MT * CSTG;
                    int oc = rem / CSTG;
                    int cpos = (rem - oc * CSTG) >> 3;
                    int arow = kx * MT + oc;
                    int dst = arow * CSTG + swz(arow, cpos);
                    long src = ((long)((ky * K + kx) * CoutT + ocg * MT + oc)) * CIN + cs + cpos * 8;
                    *(int4*)&Ash[dst] = *(const int4*)&Wh[src];
                    *(int4*)&Asl[dst] = *(const int4*)&Wl[src];
                }
            }
            __syncthreads();
#pragma unroll
            for (int kx = 0; kx < K; ++kx) {
                half8 Ah[MF], Al[MF], Bh[NF];
#pragma unroll
                for (int mi = 0; mi < MF; ++mi) {
                    int arow = kx * MT + wm * (MT / 2) + mi * 16 + l15;
                    int ao = arow * CSTG + swz(arow, quad);
                    Ah[mi] = *(const half8*)&Ash[ao];
                    Al[mi] = *(const half8*)&Asl[ao];
                }
#pragma unroll
                for (int ni = 0; ni < NF; ++ni) {
                    int m = wn * (NPX / 2) + ni * 16 + l15;
                    int xs = (S == 1) ? (m + kx) : (m + (kx >> 1) + (kx & 1) * WS2);
                    Bh[ni] = *(const half8*)&Bsh[xs * CSTG + swz(xs, quad)];
                }
#pragma unroll
                for (int mi = 0; mi < MF; ++mi)
#pragma unroll
                    for (int ni = 0; ni < NF; ++ni) {
                        acc[mi][ni] = __builtin_amdgcn_mfma_f32_16x16x32_f16(Ah[mi], Bh[ni], acc[mi][ni], 0, 0, 0);
                        acc[mi][ni] = __builtin_amdgcn_mfma_f32_16x16x32_f16(Al[mi], Bh[ni], acc[mi][ni], 0, 0, 0);
                    }
            }
        }
    }
#pragma unroll
    for (int ni = 0; ni < NF; ++ni) {
        const int n = ox0 + wn * (NPX / 2) + ni * 16 + l15;
#pragma unroll
        for (int mi = 0; mi < MF; ++mi) {
            const int ocf = ocg * MT + wm * (MT / 2) + mi * 16 + quad * 4;
            float4 bv = *(const float4*)&bias[ocf];
            float v0 = fmaxf(acc[mi][ni][0] + bv.x, 0.f);
            float v1 = fmaxf(acc[mi][ni][1] + bv.y, 0.f);
            float v2 = fmaxf(acc[mi][ni][2] + bv.z, 0.f);
            float v3 = fmaxf(acc[mi][ni][3] + bv.w, 0.f);
            if (WRITE_CL) {
                long o = ((long)(b * Hpn + oy + NP) * Wpn + n + NP) * CoutT + ocf;
                u16x4 hv;
                hv[0] = f2h(v0); hv[1] = f2h(v1); hv[2] = f2h(v2); hv[3] = f2h(v3);
                *(u16x4*)&Oh[o] = hv;
            } else {
                long o = ((long)(b * CoutT + ocf) << 12) + (oy << 6) + n;
                Ofp[o] = v0;
                Ofp[o + 4096] = v1;
                Ofp[o + 8192] = v2;
                Ofp[o + 12288] = v3;
            }
        }
    }
}

// -------- conv5 (256->1, K3 S1 P1) + relu + gate ----------
__global__ __launch_bounds__(256) void conv5_gate_k(
    const float* __restrict__ s4, const float* __restrict__ w,
    const float* __restrict__ bias, float* __restrict__ gate)
{
    const int tid = threadIdx.x;
    const int lane = tid & 63, g = tid >> 6;
    const int oy = blockIdx.x, b = blockIdx.y;
    int ixo[3], iyo[3];
#pragma unroll
    for (int k = 0; k < 3; ++k) {
        int ix = lane + k - 1; if (ix < 0) ix = -ix; if (ix >= 64) ix = 126 - ix;
        int iy = oy + k - 1; if (iy < 0) iy = -iy; if (iy >= 64) iy = 126 - iy;
        ixo[k] = ix; iyo[k] = iy << 6;
    }
    float part = 0.f;
    const float* inb = s4 + ((long)b * 256 + g * 64) * 4096;
    const float* wg = w + g * 64 * 9;
    for (int ic = 0; ic < 64; ++ic) {
        const float* inc = inb + ic * 4096;
        const float* wc = wg + ic * 9;
#pragma unroll
        for (int ky = 0; ky < 3; ++ky)
#pragma unroll
            for (int kx = 0; kx < 3; ++kx)
                part = fmaf(wc[ky * 3 + kx], inc[iyo[ky] + ixo[kx]], part);
    }
    __shared__ float red[4][64];
    red[g][lane] = part;
    __syncthreads();
    if (tid < 64) {
        float s = bias[0] + red[0][tid] + red[1][tid] + red[2][tid] + red[3][tid];
        s = fmaxf(s, 0.f);
        gate[(b << 12) + (oy << 6) + tid] = tanf(PI_F * (tanhf(s) - 0.5f));
    }
}

// ---------------- invn[b][p] = 1/sqrt(sum_c (F+1e-7)^2) ----------------
__global__ __launch_bounds__(256) void invn_k(const float* __restrict__ F, float* __restrict__ invn)
{
    const int p = blockIdx.x * 256 + threadIdx.x;
    const int b = blockIdx.y;
    const float* Fb = F + (long)b * 524288;
    float ss = 0.f;
#pragma unroll 8
    for (int c = 0; c < 128; ++c) {
        float v = Fb[c * 4096 + p] + 1e-7f;
        ss = fmaf(v, v, ss);
    }
    invn[(b << 12) + p] = 1.0f / sqrtf(ss);
}

// -------- prep: Fo16[b][c][p] = bf16(F), Ft16[b][p][c] = bf16(F^T) ---------------
__global__ __launch_bounds__(256) void prep_bf16_k(
    const float* __restrict__ F, ushort_t* __restrict__ Fo16, ushort_t* __restrict__ Ft16)
{
    __shared__ float Ls[128][65];
    const int tid = threadIdx.x;
    const int lane = tid & 63, wv = tid >> 6;
    const int p0 = blockIdx.x * 64, b = blockIdx.y;
#pragma unroll 8
    for (int cc = 0; cc < 32; ++cc) {
        int c = wv * 32 + cc;
        long idx = ((long)b * 128 + c) * 4096 + p0 + lane;
        float v = F[idx];
        Fo16[idx] = f2bf(v);
        Ls[c][lane] = v;
    }
    __syncthreads();
#pragma unroll 8
    for (int i = 0; i < 32; ++i) {
        int flat = tid + 256 * i;
        int c = flat & 127, pl_ = flat >> 7;
        Ft16[((long)b * 4096 + p0 + pl_) * 128 + c] = f2bf(Ls[c][pl_]);
    }
}

// -------- flash attention (R21): R19 structure (frag-ordered Es, pipelined loop)
//          + 5 blocks/CU: launch_bounds(256,5), Qs 14 frags in LDS + 2 in regs. ----
__global__ __launch_bounds__(256, 5) void flash_attn_k(
    const ushort_t* __restrict__ Ft16, const ushort_t* __restrict__ Fo16,
    const float* __restrict__ invn, const float* __restrict__ gate,
    float* __restrict__ Opart, float* __restrict__ lpart)
{
    __shared__ float redS[64][4];
    __shared__ ushort_t Es[2][8 * 64 * 8];   // fragment-ordered: [buf][ni*2+ksub][lane][8]
    __shared__ ushort_t Qs[14 * 64 * 8];     // frags 0..13 of [frag=ni*4+cs][lane][8]
    const int tid = threadIdx.x, lane = tid & 63, w = tid >> 6;
    const int l15 = lane & 15, quad = lane >> 4;
    const int q0 = blockIdx.x * 64;
    const int ks = blockIdx.y, b = blockIdx.z;
    const int bp = b << 12;
    const ushort_t* Ftb = Ft16 + (long)b * 4096 * 128;
    const ushort_t* Fob = Fo16 + (long)b * 128 * 4096;

    // cooperative fill of Q fragments 0..13; frags 14,15 (ni=3,cs=2,3) in registers.
#pragma unroll
    for (int s = tid; s < 896; s += 256) {
        int f = s >> 6, ls = s & 63;
        int ni = f >> 2, cs = f & 3;
        int q = q0 + ni * 16 + (ls & 15);
        int c = cs * 32 + (ls >> 4) * 8;
        *(short8*)&Qs[s * 8] = *(const short8*)&Ftb[(long)q * 128 + c];
    }
    short8 Bqr[2];
#pragma unroll
    for (int j = 0; j < 2; ++j)
        Bqr[j] = *(const short8*)&Ftb[(long)(q0 + 48 + l15) * 128 + (2 + j) * 32 + quad * 8];

    f32x4 O[2][4];
#pragma unroll
    for (int mi = 0; mi < 2; ++mi)
#pragma unroll
        for (int ni = 0; ni < 4; ++ni) O[mi][ni] = (f32x4){0.f, 0.f, 0.f, 0.f};
    float l_acc[4] = {0.f, 0.f, 0.f, 0.f};

    // producer-side Es indices (bijection to consumer fragment layout, verified R19)
    const int fw = w >> 1;
    const int Lw = l15 + 16 * ((w & 1) * 2 + (quad >> 1));
    const int offw = (quad & 1) * 4;

    __syncthreads();

    const int p_beg = ks * 1024;

    // ---- prologue: QK(0) + exp -> Es[0] ----
    {
        const int p0 = p_beg;
        float4 iv = *(const float4*)&invn[bp + p0 + w * 16 + quad * 4];
        float4 gt = *(const float4*)&gate[bp + p0 + w * 16 + quad * 4];
        f32x4 Sa[4];
#pragma unroll
        for (int ni = 0; ni < 4; ++ni) Sa[ni] = (f32x4){0.f, 0.f, 0.f, 0.f};
#pragma unroll
        for (int cs = 0; cs < 4; ++cs) {
            short8 Ap = *(const short8*)&Ftb[(long)(p0 + w * 16 + l15) * 128 + cs * 32 + quad * 8];
#pragma unroll
            for (int ni = 0; ni < 4; ++ni) {
                const int f = ni * 4 + cs;
                short8 Bqf = (f < 14) ? *(const short8*)&Qs[(f * 64 + lane) * 8] : Bqr[f - 14];
                Sa[ni] = __builtin_amdgcn_mfma_f32_16x16x32_bf16(Ap, Bqf, Sa[ni], 0, 0, 0);
            }
        }
#pragma unroll
        for (int ni = 0; ni < 4; ++ni) {
            float e0 = __expf(fmaf(Sa[ni][0], iv.x, gt.x));
            float e1 = __expf(fmaf(Sa[ni][1], iv.y, gt.y));
            float e2 = __expf(fmaf(Sa[ni][2], iv.z, gt.z));
            float e3 = __expf(fmaf(Sa[ni][3], iv.w, gt.w));
            union { u16x4 v; __hip_bfloat162 h[2]; } u;
            u.h[0] = __float22bfloat162_rn(make_float2(e0, e1));
            u.h[1] = __float22bfloat162_rn(make_float2(e2, e3));
            *(u16x4*)&Es[0][((ni * 2 + fw) * 64 + Lw) * 8 + offw] = u.v;
            l_acc[ni] += (e0 + e1) + (e2 + e3);
        }
    }
    __syncthreads();

    // ---- main loop: tile t does QK(t) and PV(t-1) ----
    int buf = 0;
    for (int t = 1; t < 16; ++t) {
        const int p0 = p_beg + t * 64;
        const int p0p = p0 - 64;
        // early global loads: PV A-operand (prev tile) + softmax scalars (cur tile)
        short8 Ac[2][2];
#pragma unroll
        for (int ksub = 0; ksub < 2; ++ksub)
#pragma unroll
            for (int mi = 0; mi < 2; ++mi)
                Ac[ksub][mi] = *(const short8*)&Fob[(long)(w * 32 + mi * 16 + l15) * 4096 + p0p + ksub * 32 + quad * 8];
        float4 iv = *(const float4*)&invn[bp + p0 + w * 16 + quad * 4];
        float4 gt = *(const float4*)&gate[bp + p0 + w * 16 + quad * 4];
        // QK(t)
        f32x4 Sa[4];
#pragma unroll
        for (int ni = 0; ni < 4; ++ni) Sa[ni] = (f32x4){0.f, 0.f, 0.f, 0.f};
#pragma unroll
        for (int cs = 0; cs < 4; ++cs) {
            short8 Ap = *(const short8*)&Ftb[(long)(p0 + w * 16 + l15) * 128 + cs * 32 + quad * 8];
#pragma unroll
            for (int ni = 0; ni < 4; ++ni) {
                const int f = ni * 4 + cs;
                short8 Bqf = (f < 14) ? *(const short8*)&Qs[(f * 64 + lane) * 8] : Bqr[f - 14];
                Sa[ni] = __builtin_amdgcn_mfma_f32_16x16x32_bf16(Ap, Bqf, Sa[ni], 0, 0, 0);
            }
        }
        // PV(t-1) from Es[buf] (written+barriered last iteration)
#pragma unroll
        for (int ksub = 0; ksub < 2; ++ksub) {
            short8 Be[4];
#pragma unroll
            for (int ni = 0; ni < 4; ++ni)
                Be[ni] = *(const short8*)&Es[buf][((ni * 2 + ksub) * 64 + lane) * 8];
#pragma unroll
            for (int mi = 0; mi < 2; ++mi)
#pragma unroll
                for (int ni = 0; ni < 4; ++ni)
                    O[mi][ni] = __builtin_amdgcn_mfma_f32_16x16x32_bf16(Ac[ksub][mi], Be[ni], O[mi][ni], 0, 0, 0);
        }
        // exp(t) -> Es[buf^1]
#pragma unroll
        for (int ni = 0; ni < 4; ++ni) {
            float e0 = __expf(fmaf(Sa[ni][0], iv.x, gt.x));
            float e1 = __expf(fmaf(Sa[ni][1], iv.y, gt.y));
            float e2 = __expf(fmaf(Sa[ni][2], iv.z, gt.z));
            float e3 = __expf(fmaf(Sa[ni][3], iv.w, gt.w));
            union { u16x4 v; __hip_bfloat162 h[2]; } u;
            u.h[0] = __float22bfloat162_rn(make_float2(e0, e1));
            u.h[1] = __float22bfloat162_rn(make_float2(e2, e3));
            *(u16x4*)&Es[buf ^ 1][((ni * 2 + fw) * 64 + Lw) * 8 + offw] = u.v;
            l_acc[ni] += (e0 + e1) + (e2 + e3);
        }
        __syncthreads();
        buf ^= 1;
    }
    // ---- epilogue: PV(15) ----
    {
        const int p0p = p_beg + 15 * 64;
#pragma unroll
        for (int ksub = 0; ksub < 2; ++ksub) {
            short8 Ac2[2], Be[4];
#pragma unroll
            for (int mi = 0; mi < 2; ++mi)
                Ac2[mi] = *(const short8*)&Fob[(long)(w * 32 + mi * 16 + l15) * 4096 + p0p + ksub * 32 + quad * 8];
#pragma unroll
            for (int ni = 0; ni < 4; ++ni)
                Be[ni] = *(const short8*)&Es[buf][((ni * 2 + ksub) * 64 + lane) * 8];
#pragma unroll
            for (int mi = 0; mi < 2; ++mi)
#pragma unroll
                for (int ni = 0; ni < 4; ++ni)
                    O[mi][ni] = __builtin_amdgcn_mfma_f32_16x16x32_bf16(Ac2[mi], Be[ni], O[mi][ni], 0, 0, 0);
        }
    }
#pragma unroll
    for (int ni = 0; ni < 4; ++ni) {
        float lt = l_acc[ni];
        lt += __shfl_xor(lt, 16);
        lt += __shfl_xor(lt, 32);
        if (quad == 0) redS[ni * 16 + l15][w] = lt;
    }
    __syncthreads();
    if (w == 0 && quad == 0) {
#pragma unroll
        for (int ni = 0; ni < 4; ++ni) {
            int q = q0 + ni * 16 + l15;
            float4 rs = *(const float4*)&redS[ni * 16 + l15][0];
            lpart[(ks * 8 + b) * 4096 + q] = (rs.x + rs.y) + (rs.z + rs.w);
        }
    }
    float* Ob = Opart + (long)(ks * 8 + b) * 524288;
#pragma unroll
    for (int mi = 0; mi < 2; ++mi)
#pragma unroll
        for (int ni = 0; ni < 4; ++ni) {
            int c = w * 32 + mi * 16 + quad * 4;
            int q = q0 + ni * 16 + l15;
#pragma unroll
            for (int r = 0; r < 4; ++r)
                Ob[((long)(c + r) << 12) + q] = O[mi][ni][r];
        }
}

// ---------------- combiner: merge 4 split-K partials ----------------
__global__ __launch_bounds__(256) void combiner_k(
    const float* __restrict__ Opart, const float* __restrict__ lpart,
    const float* __restrict__ F, const float* __restrict__ cw,
    const float* __restrict__ cb, float* __restrict__ out)
{
    const int tid = threadIdx.x;
    const int q = blockIdx.x * 256 + tid;
    const int o0 = blockIdx.y << 4;
    const int b = blockIdx.z;
    float lsum = 0.f;
#pragma unroll
    for (int ks = 0; ks < 4; ++ks) lsum += lpart[(ks * 8 + b) * 4096 + q];
    float il = 1.0f / lsum;
    const float* Fb = F + (long)b * 524288 + q;
    float acc[16];
#pragma unroll
    for (int j = 0; j < 16; ++j) acc[j] = cb[o0 + j];
    for (int c = 0; c < 128; ++c) {
        float a = 0.f;
#pragma unroll
        for (int ks = 0; ks < 4; ++ks)
            a += Opart[(long)(ks * 8 + b) * 524288 + (long)c * 4096 + q];
        a *= il;
        float f = Fb[(long)c * 4096];
#pragma unroll
        for (int j = 0; j < 16; ++j) {
            acc[j] = fmaf(cw[(o0 + j) * 256 + c], a, acc[j]);
            acc[j] = fmaf(cw[(o0 + j) * 256 + 128 + c], f, acc[j]);
        }
    }
#pragma unroll
    for (int j = 0; j < 16; ++j)
        out[((long)(b * 128 + o0 + j) << 12) + q] = acc[j];
}

// =====================================================================================
extern "C" void kernel_launch(void* const* d_in, const int* in_sizes, int n_in,
                              void* d_out, int out_size, void* d_ws, size_t ws_size,
                              hipStream_t stream)
{
    const float* F     = (const float*)d_in[0];
    const float* imgs  = (const float*)d_in[1];
    const float* masks = (const float*)d_in[2];
    const float* gw1 = (const float*)d_in[3];  const float* gb1 = (const float*)d_in[4];
    const float* gw2 = (const float*)d_in[5];  const float* gb2 = (const float*)d_in[6];
    const float* gw3 = (const float*)d_in[7];  const float* gb3 = (const float*)d_in[8];
    const float* gw4 = (const float*)d_in[9];  const float* gb4 = (const float*)d_in[10];
    const float* gw5 = (const float*)d_in[11]; const float* gb5 = (const float*)d_in[12];
    const float* cw  = (const float*)d_in[13]; const float* cb  = (const float*)d_in[14];
    float* out = (float*)d_out;

    // ---- workspace layout (float offsets), ~150 MB ----
    float* W = (float*)d_ws;
    ushort_t* Xcl2h = (ushort_t*)(W);                 // [8][260][260][32] fp16 h
    ushort_t* Xcl4h = (ushort_t*)(W);                 // [8][130][130][128] fp16 h
    float*    Opart = W;                              // [4][8][128][4096] f32
    float*    lpart = W + 16777216;                   // [4][8][4096]
    ushort_t* Xcl3h = (ushort_t*)(W + 17305600);      // [8][132][132][64] fp16 h
    ushort_t* Fo16  = (ushort_t*)(W + 17305600);      // [8][128][4096] bf16 (after conv3)
    float*    s4   = W + 26226688;                    // [8][256][64][64] f32
    ushort_t* Ft16 = (ushort_t*)(W + 30420992);       // [8][4096][128] bf16 (after conv5)
    ushort_t* W2h = (ushort_t*)(W + 34615296);
    ushort_t* W2l = (ushort_t*)(W + 34640896);
    ushort_t* W3h = (ushort_t*)(W + 34666496);
    ushort_t* W3l = (ushort_t*)(W + 34768896);
    ushort_t* W4h = (ushort_t*)(W + 34871296);
    ushort_t* W4l = (ushort_t*)(W + 35018752);
    float* gate = W + 35166208;
    float* invn = W + 35198976;
    ushort_t* Xinh = (ushort_t*)(W + 35231744);       // [8][262][262][4] fp16 h + slack
    ushort_t* W1h  = (ushort_t*)(W + 37428416);       // [7][32][32] fp16
    ushort_t* W1l  = (ushort_t*)(W + 37432000);

    // ---- weight transforms + conv1 input prep ----
    transform_w_k<<<dim3(200),  256, 0, stream>>>(gw2, W2h, W2l, 64, 32, 25);
    transform_w_k<<<dim3(800),  256, 0, stream>>>(gw3, W3h, W3l, 128, 64, 25);
    transform_w_k<<<dim3(1152), 256, 0, stream>>>(gw4, W4h, W4l, 256, 128, 9);
    transform_w1_k<<<dim3(28), 256, 0, stream>>>(gw1, W1h, W1l);
    prep_in_k<<<dim3(262, 8), 256, 0, stream>>>(imgs, masks, Xinh);

    // ---- conv stack (2-term split: weights h+l, activations h only) ----
    conv1_mfma_k<<<dim3(4, 256, 8), 256, 0, stream>>>(Xinh, W1h, W1l, gb1, Xcl2h);
    pad_cl_k<<<dim3(260, 8), 256, 0, stream>>>(Xcl2h, 260, 260, 2, 32, 256, 256);
    conv_mfma_k<5, 2, 32, 32, 64, 128, true><<<dim3(1, 128, 8), 256, 0, stream>>>(
        Xcl2h, W2h, W2l, gb2, 260, 260, 64, Xcl3h, 132, 132, 2, nullptr);
    pad_cl_k<<<dim3(132, 8), 256, 0, stream>>>(Xcl3h, 132, 132, 2, 64, 128, 128);
    conv_mfma_k<5, 1, 64, 32, 64, 128, true><<<dim3(1, 128, 16), 256, 0, stream>>>(
        Xcl3h, W3h, W3l, gb3, 132, 132, 128, Xcl4h, 130, 130, 1, nullptr);
    pad_cl_k<<<dim3(130, 8), 256, 0, stream>>>(Xcl4h, 130, 130, 1, 128, 128, 128);
    conv_mfma_k<3, 2, 128, 32, 128, 64, false><<<dim3(1, 64, 16), 256, 0, stream>>>(
        Xcl4h, W4h, W4l, gb4, 130, 130, 256, nullptr, 0, 0, 0, s4);
    conv5_gate_k<<<dim3(64, 8), 256, 0, stream>>>(s4, gw5, gb5, gate);

    // ---- attention ----
    invn_k<<<dim3(16, 8), 256, 0, stream>>>(F, invn);
    prep_bf16_k<<<dim3(64, 8), 256, 0, stream>>>(F, Fo16, Ft16);
    flash_attn_k<<<dim3(64, 4, 8), 256, 0, stream>>>(Ft16, Fo16, invn, gate, Opart, lpart);
    combiner_k<<<dim3(16, 8, 8), 256, 0, stream>>>(Opart, lpart, F, cw, cb, out);
}

// Round 7
// 644.943 us; speedup vs baseline: 1.2861x; 1.0075x over previous
//
#include <hip/hip_runtime.h>
#include <hip/hip_bf16.h>
#include <hip/hip_fp16.h>
#include <math.h>

// GatedAttention R22: single-wave barrier-free flash. R21 post-mortem: 5-block push
// failed (LDS granularity) + reg cap spilled (FETCH/WRITE up, 163us) -> revert.
// Ledger: only occupancy ever helped; the 4-wave Es-barrier structure is the wall.
// R22 = R20's verified permuted-row QK (p=(r>>2)*8+(r&3)+4sub -> lane owns
// p=quad*8+{0..7} = PV B-frag k-layout, E stays in-register) at the RIGHT tile
// shape: q=64, 1 wave/block, ni=4, O[8ct][4ni]=128 acc, Bq 64 reg,
// launch_bounds(64,1) (cap 512, no spill). Zero LDS, zero barriers -> compiler
// pipelines loads freely. Grid (8,256): blockIdx.x=b => wgid%8=b pins each
// batch's 2MB Ft+Fo to one XCD L2 (R20's FETCH blowup guard). MFMA total
// unchanged vs R19. Conv stack/combiner = R15.

#define PI_F 3.1415926f

typedef __attribute__((ext_vector_type(8))) short short8;
typedef __attribute__((ext_vector_type(4))) float f32x4;
typedef _Float16 half8 __attribute__((ext_vector_type(8)));
typedef __attribute__((ext_vector_type(4))) unsigned short u16x4;
typedef unsigned short ushort_t;

__device__ __forceinline__ ushort_t f2bf(float x) {
    unsigned u = __float_as_uint(x);
    unsigned r = (u + 0x7FFFu + ((u >> 16) & 1u)) >> 16;
    return (ushort_t)r;
}
__device__ __forceinline__ void split16(float x, ushort_t& h, ushort_t& l) {
    __half hh = __float2half(x);
    h = __half_as_ushort(hh);
    l = __half_as_ushort(__float2half(x - __half2float(hh)));
}
__device__ __forceinline__ ushort_t f2h(float x) {
    return __half_as_ushort(__float2half(x));
}
__device__ __forceinline__ int swz(int r, int c) {
    return ((c ^ r ^ (r >> 2)) & 3) << 3;
}

// ---------------- weight transform: OIHW fp32 -> [ky*kx][oc][ic] fp16 hi/lo --------
__global__ __launch_bounds__(256) void transform_w_k(
    const float* __restrict__ w, ushort_t* __restrict__ Wh, ushort_t* __restrict__ Wl,
    int Cout, int Cin, int KK)
{
    int idx = blockIdx.x * 256 + threadIdx.x;
    int N = Cout * Cin * KK;
    if (idx >= N) return;
    int oc = idx / (Cin * KK);
    int rem = idx - oc * (Cin * KK);
    int ic = rem / KK;
    int t = rem - ic * KK;
    float v = w[idx];
    long dst = ((long)t * Cout + oc) * Cin + ic;
    split16(v, Wh[dst], Wl[dst]);
}

// ------- conv1 weight transform: [32][4][7][7] -> [7 ky][32 oc][32 k=kx*4+ic] ------
__global__ __launch_bounds__(256) void transform_w1_k(
    const float* __restrict__ w, ushort_t* __restrict__ Wh, ushort_t* __restrict__ Wl)
{
    int idx = blockIdx.x * 256 + threadIdx.x;
    if (idx >= 7 * 32 * 32) return;
    int ky = idx / 1024;
    int rem = idx - ky * 1024;
    int oc = rem >> 5;
    int k = rem & 31;
    float v = 0.f;
    if (k < 28) {
        int kx = k >> 2, ic = k & 3;
        v = w[((oc * 4 + ic) * 7 + ky) * 7 + kx];
    }
    split16(v, Wh[idx], Wl[idx]);
}

// ------- prep conv1 input: reflect-pad(3) -> channel-last [8][262][262][4] fp16 h --
__global__ __launch_bounds__(256) void prep_in_k(
    const float* __restrict__ imgs, const float* __restrict__ masks,
    ushort_t* __restrict__ Xh)
{
    const int iy = blockIdx.x, b = blockIdx.y;
    int sy = iy - 3; if (sy < 0) sy = -sy; if (sy >= 256) sy = 510 - sy;
    const int rb = sy << 8;
    const float* i0 = imgs + (long)b * 3 * 65536;
    const float* mk = masks + (long)b * 65536;
    for (int x = threadIdx.x; x < 262; x += 256) {
        int sx = x - 3; if (sx < 0) sx = -sx; if (sx >= 256) sx = 510 - sx;
        u16x4 hv;
        hv[0] = f2h(i0[rb + sx]);
        hv[1] = f2h(i0[65536 + rb + sx]);
        hv[2] = f2h(i0[131072 + rb + sx]);
        hv[3] = f2h(mk[rb + sx]);
        long o = ((long)(b * 262 + iy) * 262 + x) * 4;
        *(u16x4*)&Xh[o] = hv;
    }
}

// ------- conv1 MFMA (2-term): 32 oc x 64 px per block -----------
__global__ __launch_bounds__(256) void conv1_mfma_k(
    const ushort_t* __restrict__ Xinh,
    const ushort_t* __restrict__ W1h, const ushort_t* __restrict__ W1l,
    const float* __restrict__ bias, ushort_t* __restrict__ Oh)
{
    const int tid = threadIdx.x, lane = tid & 63, wid = tid >> 6;
    const int wm = wid & 1, wn = wid >> 1, l15 = lane & 15, quad = lane >> 4;
    const int ox0 = blockIdx.x * 64;
    const int oy = blockIdx.y, b = blockIdx.z;
    f32x4 acc[2];
    acc[0] = (f32x4){0.f, 0.f, 0.f, 0.f};
    acc[1] = (f32x4){0.f, 0.f, 0.f, 0.f};
#pragma unroll
    for (int ky = 0; ky < 7; ++ky) {
        long wo = (long)(ky * 32 + wm * 16 + l15) * 32 + quad * 8;
        half8 Ah = *(const half8*)&W1h[wo];
        half8 Al = *(const half8*)&W1l[wo];
        long xrow = ((long)(b * 262 + oy + ky) * 262 + ox0) * 4;
#pragma unroll
        for (int ni = 0; ni < 2; ++ni) {
            long xo = xrow + (wn * 32 + ni * 16 + l15) * 4 + quad * 8;
            half8 Bh = *(const half8*)&Xinh[xo];
            acc[ni] = __builtin_amdgcn_mfma_f32_16x16x32_f16(Ah, Bh, acc[ni], 0, 0, 0);
            acc[ni] = __builtin_amdgcn_mfma_f32_16x16x32_f16(Al, Bh, acc[ni], 0, 0, 0);
        }
    }
    const int ocf = wm * 16 + quad * 4;
    float4 bv = *(const float4*)&bias[ocf];
#pragma unroll
    for (int ni = 0; ni < 2; ++ni) {
        int n = ox0 + wn * 32 + ni * 16 + l15;
        u16x4 hv;
        hv[0] = f2h(fmaxf(acc[ni][0] + bv.x, 0.f));
        hv[1] = f2h(fmaxf(acc[ni][1] + bv.y, 0.f));
        hv[2] = f2h(fmaxf(acc[ni][2] + bv.z, 0.f));
        hv[3] = f2h(fmaxf(acc[ni][3] + bv.w, 0.f));
        long o = ((long)(b * 260 + oy + 2) * 260 + n + 2) * 32 + ocf;
        *(u16x4*)&Oh[o] = hv;
    }
}

// ------- pad-fill for channel-last reflect-padded h-only buffers ----
__global__ __launch_bounds__(256) void pad_cl_k(
    ushort_t* __restrict__ Xh, int Hp, int Wp, int PAD, int C, int H, int W)
{
    const int iy = blockIdx.x, b = blockIdx.y;
    int t = iy - PAD; if (t < 0) t = -t; if (t >= H) t = 2 * H - 2 - t;
    const int iys = t + PAD;
    const long rowd = ((long)(b * Hp + iy) * Wp) * C;
    const long rows = ((long)(b * Hp + iys) * Wp) * C;
    const int nch = Wp * (C >> 3);
    for (int idx = threadIdx.x; idx < nch; idx += 256) {
        int x = idx / (C >> 3);
        int cg = (idx - x * (C >> 3)) << 3;
        int t2 = x - PAD; if (t2 < 0) t2 = -t2; if (t2 >= W) t2 = 2 * W - 2 - t2;
        int xs = t2 + PAD;
        if (xs == x && iys == iy) continue;
        *(int4*)&Xh[rowd + (long)x * C + cg] = *(const int4*)&Xh[rows + (long)xs * C + cg];
    }
}

// ------- MFMA conv (2-term split), swizzled LDS, de-interleave for S=2 ----
template<int K, int S, int CIN, int CSTG, int MT, int NPX, bool WRITE_CL>
__global__ __launch_bounds__(256, 2) void conv_mfma_k(
    const ushort_t* __restrict__ Xh,
    const ushort_t* __restrict__ Wh, const ushort_t* __restrict__ Wl,
    const float* __restrict__ bias,
    int Hp, int Wp, int CoutT,
    ushort_t* __restrict__ Oh, int Hpn, int Wpn, int NP,
    float* __restrict__ Ofp)
{
    constexpr int WS = (NPX - 1) * S + K;
    constexpr int WS2 = (WS + 1) / 2;
    constexpr int MF = MT / 32;
    constexpr int NF = NPX / 32;
    __shared__ ushort_t Bsh[WS * CSTG];
    __shared__ ushort_t Ash[K * MT * CSTG];
    __shared__ ushort_t Asl[K * MT * CSTG];
    const int tid = threadIdx.x, lane = tid & 63, wid = tid >> 6;
    const int wm = wid & 1, wn = wid >> 1, l15 = lane & 15, quad = lane >> 4;
    const int bx = blockIdx.x, oy = blockIdx.y;
    const int NOC = CoutT / MT;
    const int ocg = blockIdx.z % NOC, b = blockIdx.z / NOC;
    const int ox0 = bx * NPX;

    f32x4 acc[MF][NF];
#pragma unroll
    for (int mi = 0; mi < MF; ++mi)
#pragma unroll
        for (int ni = 0; ni < NF; ++ni) acc[mi][ni] = (f32x4){0.f, 0.f, 0.f, 0.f};

#pragma unroll
    for (int ky = 0; ky < K; ++ky) {
        const long rowoff = ((long)(b * Hp + oy * S + ky) * Wp + ox0 * S) * CIN;
        for (int cs = 0; cs < CIN; cs += CSTG) {
            __syncthreads();
            constexpr int NCH = WS * CSTG / 8;
#pragma unroll
            for (int it = 0; it < (NCH + 255) / 256; ++it) {
                int flat = tid + it * 256;
                if (flat < NCH) {
                    int e0 = flat * 8;
                    int x = e0 / CSTG;
                    int cpos = (e0 - x * CSTG) >> 3;
                    int xs = (S == 1) ? x : ((x >> 1) + (x & 1) * WS2);
                    *(int4*)&Bsh[xs * CSTG + swz(xs, cpos)] =
                        *(const int4*)&Xh[rowoff + (long)x * CIN + cs + cpos * 8];
                }
            }
            constexpr int NW = K * MT * CSTG / 8;
#pragma unroll
            for (int it = 0; it < (NW + 255) / 256; ++it) {
                int flat = tid + it * 256;
                if (flat < NW) {
                    int e0 = flat * 8;
                    int kx = e0 / (MT * CSTG);
                    int rem = e0 - kx * MT * CSTG;
                    int oc = rem / CSTG;
                    int cpos = (rem - oc * CSTG) >> 3;
                    int arow = kx * MT + oc;
                    int dst = arow * CSTG + swz(arow, cpos);
                    long src = ((long)((ky * K + kx) * CoutT + ocg * MT + oc)) * CIN + cs + cpos * 8;
                    *(int4*)&Ash[dst] = *(const int4*)&Wh[src];
                    *(int4*)&Asl[dst] = *(const int4*)&Wl[src];
                }
            }
            __syncthreads();
#pragma unroll
            for (int kx = 0; kx < K; ++kx) {
                half8 Ah[MF], Al[MF], Bh[NF];
#pragma unroll
                for (int mi = 0; mi < MF; ++mi) {
                    int arow = kx * MT + wm * (MT / 2) + mi * 16 + l15;
                    int ao = arow * CSTG + swz(arow, quad);
                    Ah[mi] = *(const half8*)&Ash[ao];
                    Al[mi] = *(const half8*)&Asl[ao];
                }
#pragma unroll
                for (int ni = 0; ni < NF; ++ni) {
                    int m = wn * (NPX / 2) + ni * 16 + l15;
                    int xs = (S == 1) ? (m + kx) : (m + (kx >> 1) + (kx & 1) * WS2);
                    Bh[ni] = *(const half8*)&Bsh[xs * CSTG + swz(xs, quad)];
                }
#pragma unroll
                for (int mi = 0; mi < MF; ++mi)
#pragma unroll
                    for (int ni = 0; ni < NF; ++ni) {
                        acc[mi][ni] = __builtin_amdgcn_mfma_f32_16x16x32_f16(Ah[mi], Bh[ni], acc[mi][ni], 0, 0, 0);
                        acc[mi][ni] = __builtin_amdgcn_mfma_f32_16x16x32_f16(Al[mi], Bh[ni], acc[mi][ni], 0, 0, 0);
                    }
            }
        }
    }
#pragma unroll
    for (int ni = 0; ni < NF; ++ni) {
        const int n = ox0 + wn * (NPX / 2) + ni * 16 + l15;
#pragma unroll
        for (int mi = 0; mi < MF; ++mi) {
            const int ocf = ocg * MT + wm * (MT / 2) + mi * 16 + quad * 4;
            float4 bv = *(const float4*)&bias[ocf];
            float v0 = fmaxf(acc[mi][ni][0] + bv.x, 0.f);
            float v1 = fmaxf(acc[mi][ni][1] + bv.y, 0.f);
            float v2 = fmaxf(acc[mi][ni][2] + bv.z, 0.f);
            float v3 = fmaxf(acc[mi][ni][3] + bv.w, 0.f);
            if (WRITE_CL) {
                long o = ((long)(b * Hpn + oy + NP) * Wpn + n + NP) * CoutT + ocf;
                u16x4 hv;
                hv[0] = f2h(v0); hv[1] = f2h(v1); hv[2] = f2h(v2); hv[3] = f2h(v3);
                *(u16x4*)&Oh[o] = hv;
            } else {
                long o = ((long)(b * CoutT + ocf) << 12) + (oy << 6) + n;
                Ofp[o] = v0;
                Ofp[o + 4096] = v1;
                Ofp[o + 8192] = v2;
                Ofp[o + 12288] = v3;
            }
        }
    }
}

// -------- conv5 (256->1, K3 S1 P1) + relu + gate ----------
__global__ __launch_bounds__(256) void conv5_gate_k(
    const float* __restrict__ s4, const float* __restrict__ w,
    const float* __restrict__ bias, float* __restrict__ gate)
{
    const int tid = threadIdx.x;
    const int lane = tid & 63, g = tid >> 6;
    const int oy = blockIdx.x, b = blockIdx.y;
    int ixo[3], iyo[3];
#pragma unroll
    for (int k = 0; k < 3; ++k) {
        int ix = lane + k - 1; if (ix < 0) ix = -ix; if (ix >= 64) ix = 126 - ix;
        int iy = oy + k - 1; if (iy < 0) iy = -iy; if (iy >= 64) iy = 126 - iy;
        ixo[k] = ix; iyo[k] = iy << 6;
    }
    float part = 0.f;
    const float* inb = s4 + ((long)b * 256 + g * 64) * 4096;
    const float* wg = w + g * 64 * 9;
    for (int ic = 0; ic < 64; ++ic) {
        const float* inc = inb + ic * 4096;
        const float* wc = wg + ic * 9;
#pragma unroll
        for (int ky = 0; ky < 3; ++ky)
#pragma unroll
            for (int kx = 0; kx < 3; ++kx)
                part = fmaf(wc[ky * 3 + kx], inc[iyo[ky] + ixo[kx]], part);
    }
    __shared__ float red[4][64];
    red[g][lane] = part;
    __syncthreads();
    if (tid < 64) {
        float s = bias[0] + red[0][tid] + red[1][tid] + red[2][tid] + red[3][tid];
        s = fmaxf(s, 0.f);
        gate[(b << 12) + (oy << 6) + tid] = tanf(PI_F * (tanhf(s) - 0.5f));
    }
}

// ---------------- invn[b][p] = 1/sqrt(sum_c (F+1e-7)^2) ----------------
__global__ __launch_bounds__(256) void invn_k(const float* __restrict__ F, float* __restrict__ invn)
{
    const int p = blockIdx.x * 256 + threadIdx.x;
    const int b = blockIdx.y;
    const float* Fb = F + (long)b * 524288;
    float ss = 0.f;
#pragma unroll 8
    for (int c = 0; c < 128; ++c) {
        float v = Fb[c * 4096 + p] + 1e-7f;
        ss = fmaf(v, v, ss);
    }
    invn[(b << 12) + p] = 1.0f / sqrtf(ss);
}

// -------- prep: Fo16[b][c][p] = bf16(F), Ft16[b][p][c] = bf16(F^T) ---------------
__global__ __launch_bounds__(256) void prep_bf16_k(
    const float* __restrict__ F, ushort_t* __restrict__ Fo16, ushort_t* __restrict__ Ft16)
{
    __shared__ float Ls[128][65];
    const int tid = threadIdx.x;
    const int lane = tid & 63, wv = tid >> 6;
    const int p0 = blockIdx.x * 64, b = blockIdx.y;
#pragma unroll 8
    for (int cc = 0; cc < 32; ++cc) {
        int c = wv * 32 + cc;
        long idx = ((long)b * 128 + c) * 4096 + p0 + lane;
        float v = F[idx];
        Fo16[idx] = f2bf(v);
        Ls[c][lane] = v;
    }
    __syncthreads();
#pragma unroll 8
    for (int i = 0; i < 32; ++i) {
        int flat = tid + 256 * i;
        int c = flat & 127, pl_ = flat >> 7;
        Ft16[((long)b * 4096 + p0 + pl_) * 128 + c] = f2bf(Ls[c][pl_]);
    }
}

// -------- flash attention (R22): 1 wave/block, q=64, zero LDS, zero barriers.
// Permuted-row QK (verified R20): A-row r -> Ft row p0w+(r>>2)*8+(r&3)+4*sub, so
// lane (quad,l15) holds S for p=quad*8+sub*4+{0..3} == PV B-frag k-layout.
// E: exp -> cvt_pk in-register -> PV mfma. O[8ct][4ni] accumulates 128c x 64q.
// Grid (8, 64*4): blockIdx.x = b (XCD pinning), blockIdx.y = qb + 64*ks. --------
__global__ __launch_bounds__(64, 1) void flash_attn_k(
    const ushort_t* __restrict__ Ft16, const ushort_t* __restrict__ Fo16,
    const float* __restrict__ invn, const float* __restrict__ gate,
    float* __restrict__ Opart, float* __restrict__ lpart)
{
    const int lane = threadIdx.x & 63;
    const int l15 = lane & 15, quad = lane >> 4;
    const int b = blockIdx.x;
    const int qb = blockIdx.y & 63, ks = blockIdx.y >> 6;
    const int q0 = qb * 64;
    const int bp = b << 12;
    const ushort_t* Ftb = Ft16 + (long)b * 4096 * 128;
    const ushort_t* Fob = Fo16 + (long)b * 128 * 4096;

    // Q fragments (B-operand): B[k=c][col=q], 16 frags = 64 VGPR
    short8 Bq[4][4];
#pragma unroll
    for (int ni = 0; ni < 4; ++ni)
#pragma unroll
        for (int cs = 0; cs < 4; ++cs)
            Bq[ni][cs] = *(const short8*)&Ftb[(long)(q0 + ni * 16 + l15) * 128 + cs * 32 + quad * 8];

    f32x4 O[8][4];   // [ct][ni] : c = ct*16+quad*4+r, q = q0+ni*16+l15
#pragma unroll
    for (int ct = 0; ct < 8; ++ct)
#pragma unroll
        for (int ni = 0; ni < 4; ++ni) O[ct][ni] = (f32x4){0.f, 0.f, 0.f, 0.f};
    float l_acc[4] = {0.f, 0.f, 0.f, 0.f};

    union BeU { short8 v; __hip_bfloat162 h[4]; };
    const int p_beg = ks * 1024;
    const int prow_base = ((l15 & 12) << 1) + (l15 & 3);   // (r>>2)*8 + (r&3)

    for (int t = 0; t < 32; ++t) {
        const int p0w = p_beg + t * 32;
        BeU be[4];
#pragma unroll
        for (int sub = 0; sub < 2; ++sub) {
            const long prow = p0w + prow_base + sub * 4;
            f32x4 Sa[4];
#pragma unroll
            for (int ni = 0; ni < 4; ++ni) Sa[ni] = (f32x4){0.f, 0.f, 0.f, 0.f};
#pragma unroll
            for (int cs = 0; cs < 4; ++cs) {
                short8 Ap = *(const short8*)&Ftb[prow * 128 + cs * 32 + quad * 8];
#pragma unroll
                for (int ni = 0; ni < 4; ++ni)
                    Sa[ni] = __builtin_amdgcn_mfma_f32_16x16x32_bf16(Ap, Bq[ni][cs], Sa[ni], 0, 0, 0);
            }
            // lane holds S[p = p0w + quad*8 + sub*4 + r][q = q0 + ni*16 + l15]
            float4 iv = *(const float4*)&invn[bp + p0w + quad * 8 + sub * 4];
            float4 gt = *(const float4*)&gate[bp + p0w + quad * 8 + sub * 4];
#pragma unroll
            for (int ni = 0; ni < 4; ++ni) {
                float e0 = __expf(fmaf(Sa[ni][0], iv.x, gt.x));
                float e1 = __expf(fmaf(Sa[ni][1], iv.y, gt.y));
                float e2 = __expf(fmaf(Sa[ni][2], iv.z, gt.z));
                float e3 = __expf(fmaf(Sa[ni][3], iv.w, gt.w));
                be[ni].h[sub * 2]     = __float22bfloat162_rn(make_float2(e0, e1));
                be[ni].h[sub * 2 + 1] = __float22bfloat162_rn(make_float2(e2, e3));
                l_acc[ni] += (e0 + e1) + (e2 + e3);
            }
        }
        // PV: A = V frag (row=c, k=p=quad*8+e), B = in-register E
#pragma unroll
        for (int ct = 0; ct < 8; ++ct) {
            short8 Va = *(const short8*)&Fob[(long)(ct * 16 + l15) * 4096 + p0w + quad * 8];
#pragma unroll
            for (int ni = 0; ni < 4; ++ni)
                O[ct][ni] = __builtin_amdgcn_mfma_f32_16x16x32_bf16(Va, be[ni].v, O[ct][ni], 0, 0, 0);
        }
    }

    // ---- lpart: reduce l_acc over quads (lanes with same l15 share q) ----
#pragma unroll
    for (int ni = 0; ni < 4; ++ni) {
        float lt = l_acc[ni];
        lt += __shfl_xor(lt, 16);
        lt += __shfl_xor(lt, 32);
        if (quad == 0)
            lpart[(ks * 8 + b) * 4096 + q0 + ni * 16 + l15] = lt;
    }
    // ---- O write: per (ct,ni,r), 16 lanes write 16 consecutive q (64B) ----
    float* Ob = Opart + (long)(ks * 8 + b) * 524288;
#pragma unroll
    for (int ct = 0; ct < 8; ++ct)
#pragma unroll
        for (int ni = 0; ni < 4; ++ni) {
            int c = ct * 16 + quad * 4;
            int q = q0 + ni * 16 + l15;
#pragma unroll
            for (int r = 0; r < 4; ++r)
                Ob[((long)(c + r) << 12) + q] = O[ct][ni][r];
        }
}

// ---------------- combiner: merge 4 split-K partials ----------------
__global__ __launch_bounds__(256) void combiner_k(
    const float* __restrict__ Opart, const float* __restrict__ lpart,
    const float* __restrict__ F, const float* __restrict__ cw,
    const float* __restrict__ cb, float* __restrict__ out)
{
    const int tid = threadIdx.x;
    const int q = blockIdx.x * 256 + tid;
    const int o0 = blockIdx.y << 4;
    const int b = blockIdx.z;
    float lsum = 0.f;
#pragma unroll
    for (int ks = 0; ks < 4; ++ks) lsum += lpart[(ks * 8 + b) * 4096 + q];
    float il = 1.0f / lsum;
    const float* Fb = F + (long)b * 524288 + q;
    float acc[16];
#pragma unroll
    for (int j = 0; j < 16; ++j) acc[j] = cb[o0 + j];
    for (int c = 0; c < 128; ++c) {
        float a = 0.f;
#pragma unroll
        for (int ks = 0; ks < 4; ++ks)
            a += Opart[(long)(ks * 8 + b) * 524288 + (long)c * 4096 + q];
        a *= il;
        float f = Fb[(long)c * 4096];
#pragma unroll
        for (int j = 0; j < 16; ++j) {
            acc[j] = fmaf(cw[(o0 + j) * 256 + c], a, acc[j]);
            acc[j] = fmaf(cw[(o0 + j) * 256 + 128 + c], f, acc[j]);
        }
    }
#pragma unroll
    for (int j = 0; j < 16; ++j)
        out[((long)(b * 128 + o0 + j) << 12) + q] = acc[j];
}

// =====================================================================================
extern "C" void kernel_launch(void* const* d_in, const int* in_sizes, int n_in,
                              void* d_out, int out_size, void* d_ws, size_t ws_size,
                              hipStream_t stream)
{
    const float* F     = (const float*)d_in[0];
    const float* imgs  = (const float*)d_in[1];
    const float* masks = (const float*)d_in[2];
    const float* gw1 = (const float*)d_in[3];  const float* gb1 = (const float*)d_in[4];
    const float* gw2 = (const float*)d_in[5];  const float* gb2 = (const float*)d_in[6];
    const float* gw3 = (const float*)d_in[7];  const float* gb3 = (const float*)d_in[8];
    const float* gw4 = (const float*)d_in[9];  const float* gb4 = (const float*)d_in[10];
    const float* gw5 = (const float*)d_in[11]; const float* gb5 = (const float*)d_in[12];
    const float* cw  = (const float*)d_in[13]; const float* cb  = (const float*)d_in[14];
    float* out = (float*)d_out;

    // ---- workspace layout (float offsets), ~150 MB ----
    float* W = (float*)d_ws;
    ushort_t* Xcl2h = (ushort_t*)(W);                 // [8][260][260][32] fp16 h
    ushort_t* Xcl4h = (ushort_t*)(W);                 // [8][130][130][128] fp16 h
    float*    Opart = W;                              // [4][8][128][4096] f32
    float*    lpart = W + 16777216;                   // [4][8][4096]
    ushort_t* Xcl3h = (ushort_t*)(W + 17305600);      // [8][132][132][64] fp16 h
    ushort_t* Fo16  = (ushort_t*)(W + 17305600);      // [8][128][4096] bf16 (after conv3)
    float*    s4   = W + 26226688;                    // [8][256][64][64] f32
    ushort_t* Ft16 = (ushort_t*)(W + 30420992);       // [8][4096][128] bf16 (after conv5)
    ushort_t* W2h = (ushort_t*)(W + 34615296);
    ushort_t* W2l = (ushort_t*)(W + 34640896);
    ushort_t* W3h = (ushort_t*)(W + 34666496);
    ushort_t* W3l = (ushort_t*)(W + 34768896);
    ushort_t* W4h = (ushort_t*)(W + 34871296);
    ushort_t* W4l = (ushort_t*)(W + 35018752);
    float* gate = W + 35166208;
    float* invn = W + 35198976;
    ushort_t* Xinh = (ushort_t*)(W + 35231744);       // [8][262][262][4] fp16 h + slack
    ushort_t* W1h  = (ushort_t*)(W + 37428416);       // [7][32][32] fp16
    ushort_t* W1l  = (ushort_t*)(W + 37432000);

    // ---- weight transforms + conv1 input prep ----
    transform_w_k<<<dim3(200),  256, 0, stream>>>(gw2, W2h, W2l, 64, 32, 25);
    transform_w_k<<<dim3(800),  256, 0, stream>>>(gw3, W3h, W3l, 128, 64, 25);
    transform_w_k<<<dim3(1152), 256, 0, stream>>>(gw4, W4h, W4l, 256, 128, 9);
    transform_w1_k<<<dim3(28), 256, 0, stream>>>(gw1, W1h, W1l);
    prep_in_k<<<dim3(262, 8), 256, 0, stream>>>(imgs, masks, Xinh);

    // ---- conv stack (2-term split: weights h+l, activations h only) ----
    conv1_mfma_k<<<dim3(4, 256, 8), 256, 0, stream>>>(Xinh, W1h, W1l, gb1, Xcl2h);
    pad_cl_k<<<dim3(260, 8), 256, 0, stream>>>(Xcl2h, 260, 260, 2, 32, 256, 256);
    conv_mfma_k<5, 2, 32, 32, 64, 128, true><<<dim3(1, 128, 8), 256, 0, stream>>>(
        Xcl2h, W2h, W2l, gb2, 260, 260, 64, Xcl3h, 132, 132, 2, nullptr);
    pad_cl_k<<<dim3(132, 8), 256, 0, stream>>>(Xcl3h, 132, 132, 2, 64, 128, 128);
    conv_mfma_k<5, 1, 64, 32, 64, 128, true><<<dim3(1, 128, 16), 256, 0, stream>>>(
        Xcl3h, W3h, W3l, gb3, 132, 132, 128, Xcl4h, 130, 130, 1, nullptr);
    pad_cl_k<<<dim3(130, 8), 256, 0, stream>>>(Xcl4h, 130, 130, 1, 128, 128, 128);
    conv_mfma_k<3, 2, 128, 32, 128, 64, false><<<dim3(1, 64, 16), 256, 0, stream>>>(
        Xcl4h, W4h, W4l, gb4, 130, 130, 256, nullptr, 0, 0, 0, s4);
    conv5_gate_k<<<dim3(64, 8), 256, 0, stream>>>(s4, gw5, gb5, gate);

    // ---- attention ----
    invn_k<<<dim3(16, 8), 256, 0, stream>>>(F, invn);
    prep_bf16_k<<<dim3(64, 8), 256, 0, stream>>>(F, Fo16, Ft16);
    flash_attn_k<<<dim3(8, 256, 1), 64, 0, stream>>>(Ft16, Fo16, invn, gate, Opart, lpart);
    combiner_k<<<dim3(16, 8, 8), 256, 0, stream>>>(Opart, lpart, F, cw, cb, out);
}

// Round 8
// 632.876 us; speedup vs baseline: 1.3106x; 1.0191x over previous
//
#include <hip/hip_runtime.h>
#include <hip/hip_bf16.h>
#include <hip/hip_fp16.h>
#include <math.h>

// GatedAttention R23: R22 + manual register double-buffer (ILP pipeline).
// R22 post-mortem: XCD-pinning worked (FETCH 68.7->10.9 MB, reads now L2-resident)
// but unified regs 168+128acc=296>256 -> hard 1 wave/SIMD, and the serial chain
// Ap->QK->exp->Va->PV exposes an L2 latency per stage (85% of time = stall;
// 4.7K cyc/iter vs 620 compute). Fix: ping-pong operand buffers -- issue ALL of
// iteration t+1's loads (Ap/Va/iv/gt) before computing iteration t; each load
// gets a full body (~600cyc) to land. unroll-2 makes buf=t&1 static (rule #20).
// Regs ~410 <= 512, still 1 wave/SIMD by design (ILP replaces TLP).
// Floor: compute ~17us, L2-read ~31us -> target 55-85us (from 150).
// Conv stack/combiner = R15.

#define PI_F 3.1415926f

typedef __attribute__((ext_vector_type(8))) short short8;
typedef __attribute__((ext_vector_type(4))) float f32x4;
typedef _Float16 half8 __attribute__((ext_vector_type(8)));
typedef __attribute__((ext_vector_type(4))) unsigned short u16x4;
typedef unsigned short ushort_t;

__device__ __forceinline__ ushort_t f2bf(float x) {
    unsigned u = __float_as_uint(x);
    unsigned r = (u + 0x7FFFu + ((u >> 16) & 1u)) >> 16;
    return (ushort_t)r;
}
__device__ __forceinline__ void split16(float x, ushort_t& h, ushort_t& l) {
    __half hh = __float2half(x);
    h = __half_as_ushort(hh);
    l = __half_as_ushort(__float2half(x - __half2float(hh)));
}
__device__ __forceinline__ ushort_t f2h(float x) {
    return __half_as_ushort(__float2half(x));
}
__device__ __forceinline__ int swz(int r, int c) {
    return ((c ^ r ^ (r >> 2)) & 3) << 3;
}

// ---------------- weight transform: OIHW fp32 -> [ky*kx][oc][ic] fp16 hi/lo --------
__global__ __launch_bounds__(256) void transform_w_k(
    const float* __restrict__ w, ushort_t* __restrict__ Wh, ushort_t* __restrict__ Wl,
    int Cout, int Cin, int KK)
{
    int idx = blockIdx.x * 256 + threadIdx.x;
    int N = Cout * Cin * KK;
    if (idx >= N) return;
    int oc = idx / (Cin * KK);
    int rem = idx - oc * (Cin * KK);
    int ic = rem / KK;
    int t = rem - ic * KK;
    float v = w[idx];
    long dst = ((long)t * Cout + oc) * Cin + ic;
    split16(v, Wh[dst], Wl[dst]);
}

// ------- conv1 weight transform: [32][4][7][7] -> [7 ky][32 oc][32 k=kx*4+ic] ------
__global__ __launch_bounds__(256) void transform_w1_k(
    const float* __restrict__ w, ushort_t* __restrict__ Wh, ushort_t* __restrict__ Wl)
{
    int idx = blockIdx.x * 256 + threadIdx.x;
    if (idx >= 7 * 32 * 32) return;
    int ky = idx / 1024;
    int rem = idx - ky * 1024;
    int oc = rem >> 5;
    int k = rem & 31;
    float v = 0.f;
    if (k < 28) {
        int kx = k >> 2, ic = k & 3;
        v = w[((oc * 4 + ic) * 7 + ky) * 7 + kx];
    }
    split16(v, Wh[idx], Wl[idx]);
}

// ------- prep conv1 input: reflect-pad(3) -> channel-last [8][262][262][4] fp16 h --
__global__ __launch_bounds__(256) void prep_in_k(
    const float* __restrict__ imgs, const float* __restrict__ masks,
    ushort_t* __restrict__ Xh)
{
    const int iy = blockIdx.x, b = blockIdx.y;
    int sy = iy - 3; if (sy < 0) sy = -sy; if (sy >= 256) sy = 510 - sy;
    const int rb = sy << 8;
    const float* i0 = imgs + (long)b * 3 * 65536;
    const float* mk = masks + (long)b * 65536;
    for (int x = threadIdx.x; x < 262; x += 256) {
        int sx = x - 3; if (sx < 0) sx = -sx; if (sx >= 256) sx = 510 - sx;
        u16x4 hv;
        hv[0] = f2h(i0[rb + sx]);
        hv[1] = f2h(i0[65536 + rb + sx]);
        hv[2] = f2h(i0[131072 + rb + sx]);
        hv[3] = f2h(mk[rb + sx]);
        long o = ((long)(b * 262 + iy) * 262 + x) * 4;
        *(u16x4*)&Xh[o] = hv;
    }
}

// ------- conv1 MFMA (2-term): 32 oc x 64 px per block -----------
__global__ __launch_bounds__(256) void conv1_mfma_k(
    const ushort_t* __restrict__ Xinh,
    const ushort_t* __restrict__ W1h, const ushort_t* __restrict__ W1l,
    const float* __restrict__ bias, ushort_t* __restrict__ Oh)
{
    const int tid = threadIdx.x, lane = tid & 63, wid = tid >> 6;
    const int wm = wid & 1, wn = wid >> 1, l15 = lane & 15, quad = lane >> 4;
    const int ox0 = blockIdx.x * 64;
    const int oy = blockIdx.y, b = blockIdx.z;
    f32x4 acc[2];
    acc[0] = (f32x4){0.f, 0.f, 0.f, 0.f};
    acc[1] = (f32x4){0.f, 0.f, 0.f, 0.f};
#pragma unroll
    for (int ky = 0; ky < 7; ++ky) {
        long wo = (long)(ky * 32 + wm * 16 + l15) * 32 + quad * 8;
        half8 Ah = *(const half8*)&W1h[wo];
        half8 Al = *(const half8*)&W1l[wo];
        long xrow = ((long)(b * 262 + oy + ky) * 262 + ox0) * 4;
#pragma unroll
        for (int ni = 0; ni < 2; ++ni) {
            long xo = xrow + (wn * 32 + ni * 16 + l15) * 4 + quad * 8;
            half8 Bh = *(const half8*)&Xinh[xo];
            acc[ni] = __builtin_amdgcn_mfma_f32_16x16x32_f16(Ah, Bh, acc[ni], 0, 0, 0);
            acc[ni] = __builtin_amdgcn_mfma_f32_16x16x32_f16(Al, Bh, acc[ni], 0, 0, 0);
        }
    }
    const int ocf = wm * 16 + quad * 4;
    float4 bv = *(const float4*)&bias[ocf];
#pragma unroll
    for (int ni = 0; ni < 2; ++ni) {
        int n = ox0 + wn * 32 + ni * 16 + l15;
        u16x4 hv;
        hv[0] = f2h(fmaxf(acc[ni][0] + bv.x, 0.f));
        hv[1] = f2h(fmaxf(acc[ni][1] + bv.y, 0.f));
        hv[2] = f2h(fmaxf(acc[ni][2] + bv.z, 0.f));
        hv[3] = f2h(fmaxf(acc[ni][3] + bv.w, 0.f));
        long o = ((long)(b * 260 + oy + 2) * 260 + n + 2) * 32 + ocf;
        *(u16x4*)&Oh[o] = hv;
    }
}

// ------- pad-fill for channel-last reflect-padded h-only buffers ----
__global__ __launch_bounds__(256) void pad_cl_k(
    ushort_t* __restrict__ Xh, int Hp, int Wp, int PAD, int C, int H, int W)
{
    const int iy = blockIdx.x, b = blockIdx.y;
    int t = iy - PAD; if (t < 0) t = -t; if (t >= H) t = 2 * H - 2 - t;
    const int iys = t + PAD;
    const long rowd = ((long)(b * Hp + iy) * Wp) * C;
    const long rows = ((long)(b * Hp + iys) * Wp) * C;
    const int nch = Wp * (C >> 3);
    for (int idx = threadIdx.x; idx < nch; idx += 256) {
        int x = idx / (C >> 3);
        int cg = (idx - x * (C >> 3)) << 3;
        int t2 = x - PAD; if (t2 < 0) t2 = -t2; if (t2 >= W) t2 = 2 * W - 2 - t2;
        int xs = t2 + PAD;
        if (xs == x && iys == iy) continue;
        *(int4*)&Xh[rowd + (long)x * C + cg] = *(const int4*)&Xh[rows + (long)xs * C + cg];
    }
}

// ------- MFMA conv (2-term split), swizzled LDS, de-interleave for S=2 ----
template<int K, int S, int CIN, int CSTG, int MT, int NPX, bool WRITE_CL>
__global__ __launch_bounds__(256, 2) void conv_mfma_k(
    const ushort_t* __restrict__ Xh,
    const ushort_t* __restrict__ Wh, const ushort_t* __restrict__ Wl,
    const float* __restrict__ bias,
    int Hp, int Wp, int CoutT,
    ushort_t* __restrict__ Oh, int Hpn, int Wpn, int NP,
    float* __restrict__ Ofp)
{
    constexpr int WS = (NPX - 1) * S + K;
    constexpr int WS2 = (WS + 1) / 2;
    constexpr int MF = MT / 32;
    constexpr int NF = NPX / 32;
    __shared__ ushort_t Bsh[WS * CSTG];
    __shared__ ushort_t Ash[K * MT * CSTG];
    __shared__ ushort_t Asl[K * MT * CSTG];
    const int tid = threadIdx.x, lane = tid & 63, wid = tid >> 6;
    const int wm = wid & 1, wn = wid >> 1, l15 = lane & 15, quad = lane >> 4;
    const int bx = blockIdx.x, oy = blockIdx.y;
    const int NOC = CoutT / MT;
    const int ocg = blockIdx.z % NOC, b = blockIdx.z / NOC;
    const int ox0 = bx * NPX;

    f32x4 acc[MF][NF];
#pragma unroll
    for (int mi = 0; mi < MF; ++mi)
#pragma unroll
        for (int ni = 0; ni < NF; ++ni) acc[mi][ni] = (f32x4){0.f, 0.f, 0.f, 0.f};

#pragma unroll
    for (int ky = 0; ky < K; ++ky) {
        const long rowoff = ((long)(b * Hp + oy * S + ky) * Wp + ox0 * S) * CIN;
        for (int cs = 0; cs < CIN; cs += CSTG) {
            __syncthreads();
            constexpr int NCH = WS * CSTG / 8;
#pragma unroll
            for (int it = 0; it < (NCH + 255) / 256; ++it) {
                int flat = tid + it * 256;
                if (flat < NCH) {
                    int e0 = flat * 8;
                    int x = e0 / CSTG;
                    int cpos = (e0 - x * CSTG) >> 3;
                    int xs = (S == 1) ? x : ((x >> 1) + (x & 1) * WS2);
                    *(int4*)&Bsh[xs * CSTG + swz(xs, cpos)] =
                        *(const int4*)&Xh[rowoff + (long)x * CIN + cs + cpos * 8];
                }
            }
            constexpr int NW = K * MT * CSTG / 8;
#pragma unroll
            for (int it = 0; it < (NW + 255) / 256; ++it) {
                int flat = tid + it * 256;
                if (flat < NW) {
                    int e0 = flat * 8;
                    int kx = e0 / (MT * CSTG);
                    int rem = e0 - kx * MT * CSTG;
                    int oc = rem / CSTG;
                    int cpos = (rem - oc * CSTG) >> 3;
                    int arow = kx * MT + oc;
                    int dst = arow * CSTG + swz(arow, cpos);
                    long src = ((long)((ky * K + kx) * CoutT + ocg * MT + oc)) * CIN + cs + cpos * 8;
                    *(int4*)&Ash[dst] = *(const int4*)&Wh[src];
                    *(int4*)&Asl[dst] = *(const int4*)&Wl[src];
                }
            }
            __syncthreads();
#pragma unroll
            for (int kx = 0; kx < K; ++kx) {
                half8 Ah[MF], Al[MF], Bh[NF];
#pragma unroll
                for (int mi = 0; mi < MF; ++mi) {
                    int arow = kx * MT + wm * (MT / 2) + mi * 16 + l15;
                    int ao = arow * CSTG + swz(arow, quad);
                    Ah[mi] = *(const half8*)&Ash[ao];
                    Al[mi] = *(const half8*)&Asl[ao];
                }
#pragma unroll
                for (int ni = 0; ni < NF; ++ni) {
                    int m = wn * (NPX / 2) + ni * 16 + l15;
                    int xs = (S == 1) ? (m + kx) : (m + (kx >> 1) + (kx & 1) * WS2);
                    Bh[ni] = *(const half8*)&Bsh[xs * CSTG + swz(xs, quad)];
                }
#pragma unroll
                for (int mi = 0; mi < MF; ++mi)
#pragma unroll
                    for (int ni = 0; ni < NF; ++ni) {
                        acc[mi][ni] = __builtin_amdgcn_mfma_f32_16x16x32_f16(Ah[mi], Bh[ni], acc[mi][ni], 0, 0, 0);
                        acc[mi][ni] = __builtin_amdgcn_mfma_f32_16x16x32_f16(Al[mi], Bh[ni], acc[mi][ni], 0, 0, 0);
                    }
            }
        }
    }
#pragma unroll
    for (int ni = 0; ni < NF; ++ni) {
        const int n = ox0 + wn * (NPX / 2) + ni * 16 + l15;
#pragma unroll
        for (int mi = 0; mi < MF; ++mi) {
            const int ocf = ocg * MT + wm * (MT / 2) + mi * 16 + quad * 4;
            float4 bv = *(const float4*)&bias[ocf];
            float v0 = fmaxf(acc[mi][ni][0] + bv.x, 0.f);
            float v1 = fmaxf(acc[mi][ni][1] + bv.y, 0.f);
            float v2 = fmaxf(acc[mi][ni][2] + bv.z, 0.f);
            float v3 = fmaxf(acc[mi][ni][3] + bv.w, 0.f);
            if (WRITE_CL) {
                long o = ((long)(b * Hpn + oy + NP) * Wpn + n + NP) * CoutT + ocf;
                u16x4 hv;
                hv[0] = f2h(v0); hv[1] = f2h(v1); hv[2] = f2h(v2); hv[3] = f2h(v3);
                *(u16x4*)&Oh[o] = hv;
            } else {
                long o = ((long)(b * CoutT + ocf) << 12) + (oy << 6) + n;
                Ofp[o] = v0;
                Ofp[o + 4096] = v1;
                Ofp[o + 8192] = v2;
                Ofp[o + 12288] = v3;
            }
        }
    }
}

// -------- conv5 (256->1, K3 S1 P1) + relu + gate ----------
__global__ __launch_bounds__(256) void conv5_gate_k(
    const float* __restrict__ s4, const float* __restrict__ w,
    const float* __restrict__ bias, float* __restrict__ gate)
{
    const int tid = threadIdx.x;
    const int lane = tid & 63, g = tid >> 6;
    const int oy = blockIdx.x, b = blockIdx.y;
    int ixo[3], iyo[3];
#pragma unroll
    for (int k = 0; k < 3; ++k) {
        int ix = lane + k - 1; if (ix < 0) ix = -ix; if (ix >= 64) ix = 126 - ix;
        int iy = oy + k - 1; if (iy < 0) iy = -iy; if (iy >= 64) iy = 126 - iy;
        ixo[k] = ix; iyo[k] = iy << 6;
    }
    float part = 0.f;
    const float* inb = s4 + ((long)b * 256 + g * 64) * 4096;
    const float* wg = w + g * 64 * 9;
    for (int ic = 0; ic < 64; ++ic) {
        const float* inc = inb + ic * 4096;
        const float* wc = wg + ic * 9;
#pragma unroll
        for (int ky = 0; ky < 3; ++ky)
#pragma unroll
            for (int kx = 0; kx < 3; ++kx)
                part = fmaf(wc[ky * 3 + kx], inc[iyo[ky] + ixo[kx]], part);
    }
    __shared__ float red[4][64];
    red[g][lane] = part;
    __syncthreads();
    if (tid < 64) {
        float s = bias[0] + red[0][tid] + red[1][tid] + red[2][tid] + red[3][tid];
        s = fmaxf(s, 0.f);
        gate[(b << 12) + (oy << 6) + tid] = tanf(PI_F * (tanhf(s) - 0.5f));
    }
}

// ---------------- invn[b][p] = 1/sqrt(sum_c (F+1e-7)^2) ----------------
__global__ __launch_bounds__(256) void invn_k(const float* __restrict__ F, float* __restrict__ invn)
{
    const int p = blockIdx.x * 256 + threadIdx.x;
    const int b = blockIdx.y;
    const float* Fb = F + (long)b * 524288;
    float ss = 0.f;
#pragma unroll 8
    for (int c = 0; c < 128; ++c) {
        float v = Fb[c * 4096 + p] + 1e-7f;
        ss = fmaf(v, v, ss);
    }
    invn[(b << 12) + p] = 1.0f / sqrtf(ss);
}

// -------- prep: Fo16[b][c][p] = bf16(F), Ft16[b][p][c] = bf16(F^T) ---------------
__global__ __launch_bounds__(256) void prep_bf16_k(
    const float* __restrict__ F, ushort_t* __restrict__ Fo16, ushort_t* __restrict__ Ft16)
{
    __shared__ float Ls[128][65];
    const int tid = threadIdx.x;
    const int lane = tid & 63, wv = tid >> 6;
    const int p0 = blockIdx.x * 64, b = blockIdx.y;
#pragma unroll 8
    for (int cc = 0; cc < 32; ++cc) {
        int c = wv * 32 + cc;
        long idx = ((long)b * 128 + c) * 4096 + p0 + lane;
        float v = F[idx];
        Fo16[idx] = f2bf(v);
        Ls[c][lane] = v;
    }
    __syncthreads();
#pragma unroll 8
    for (int i = 0; i < 32; ++i) {
        int flat = tid + 256 * i;
        int c = flat & 127, pl_ = flat >> 7;
        Ft16[((long)b * 4096 + p0 + pl_) * 128 + c] = f2bf(Ls[c][pl_]);
    }
}

// -------- flash attention (R23): R22 + register double-buffer ILP pipeline.
// 1 wave/block, q=64, zero LDS/barriers; per iteration issue t+1's Ap/Va/iv/gt
// into the nxt buffer BEFORE computing t from cur. unroll-2 -> static buf idx. ----
__global__ __launch_bounds__(64, 1) void flash_attn_k(
    const ushort_t* __restrict__ Ft16, const ushort_t* __restrict__ Fo16,
    const float* __restrict__ invn, const float* __restrict__ gate,
    float* __restrict__ Opart, float* __restrict__ lpart)
{
    const int lane = threadIdx.x & 63;
    const int l15 = lane & 15, quad = lane >> 4;
    const int b = blockIdx.x;
    const int qb = blockIdx.y & 63, ks = blockIdx.y >> 6;
    const int q0 = qb * 64;
    const int bp = b << 12;
    const ushort_t* Ftb = Ft16 + (long)b * 4096 * 128;
    const ushort_t* Fob = Fo16 + (long)b * 128 * 4096;

    // Q fragments (B-operand): B[k=c][col=q], 16 frags = 64 VGPR
    short8 Bq[4][4];
#pragma unroll
    for (int ni = 0; ni < 4; ++ni)
#pragma unroll
        for (int cs = 0; cs < 4; ++cs)
            Bq[ni][cs] = *(const short8*)&Ftb[(long)(q0 + ni * 16 + l15) * 128 + cs * 32 + quad * 8];

    f32x4 O[8][4];   // [ct][ni] : c = ct*16+quad*4+r, q = q0+ni*16+l15
#pragma unroll
    for (int ct = 0; ct < 8; ++ct)
#pragma unroll
        for (int ni = 0; ni < 4; ++ni) O[ct][ni] = (f32x4){0.f, 0.f, 0.f, 0.f};
    float l_acc[4] = {0.f, 0.f, 0.f, 0.f};

    union BeU { short8 v; __hip_bfloat162 h[4]; };
    const int p_beg = ks * 1024;
    const int prow_base = ((l15 & 12) << 1) + (l15 & 3);   // (r>>2)*8 + (r&3)

    // ---- double-buffered operand registers ----
    short8 Ap[2][2][4];      // [buf][sub][cs]
    short8 Va[2][8];         // [buf][ct]
    float4 ivb[2][2], gtb[2][2];  // [buf][sub]

    // prologue: fill buf 0 for t=0
    {
        const int p0w = p_beg;
#pragma unroll
        for (int sub = 0; sub < 2; ++sub) {
            const long prow = p0w + prow_base + sub * 4;
#pragma unroll
            for (int cs = 0; cs < 4; ++cs)
                Ap[0][sub][cs] = *(const short8*)&Ftb[prow * 128 + cs * 32 + quad * 8];
            ivb[0][sub] = *(const float4*)&invn[bp + p0w + quad * 8 + sub * 4];
            gtb[0][sub] = *(const float4*)&gate[bp + p0w + quad * 8 + sub * 4];
        }
#pragma unroll
        for (int ct = 0; ct < 8; ++ct)
            Va[0][ct] = *(const short8*)&Fob[(long)(ct * 16 + l15) * 4096 + p0w + quad * 8];
    }

#pragma unroll 2
    for (int t = 0; t < 32; ++t) {
        const int cur = t & 1, nxt = cur ^ 1;   // compile-time after unroll-2
        // ---- issue next-iteration loads first (latency hides under compute) ----
        if (t + 1 < 32) {
            const int p1 = p_beg + (t + 1) * 32;
#pragma unroll
            for (int sub = 0; sub < 2; ++sub) {
                const long prow = p1 + prow_base + sub * 4;
#pragma unroll
                for (int cs = 0; cs < 4; ++cs)
                    Ap[nxt][sub][cs] = *(const short8*)&Ftb[prow * 128 + cs * 32 + quad * 8];
                ivb[nxt][sub] = *(const float4*)&invn[bp + p1 + quad * 8 + sub * 4];
                gtb[nxt][sub] = *(const float4*)&gate[bp + p1 + quad * 8 + sub * 4];
            }
#pragma unroll
            for (int ct = 0; ct < 8; ++ct)
                Va[nxt][ct] = *(const short8*)&Fob[(long)(ct * 16 + l15) * 4096 + p1 + quad * 8];
        }
        // ---- QK + exp from buf cur ----
        BeU be[4];
#pragma unroll
        for (int sub = 0; sub < 2; ++sub) {
            f32x4 Sa[4];
#pragma unroll
            for (int ni = 0; ni < 4; ++ni) Sa[ni] = (f32x4){0.f, 0.f, 0.f, 0.f};
#pragma unroll
            for (int cs = 0; cs < 4; ++cs)
#pragma unroll
                for (int ni = 0; ni < 4; ++ni)
                    Sa[ni] = __builtin_amdgcn_mfma_f32_16x16x32_bf16(Ap[cur][sub][cs], Bq[ni][cs], Sa[ni], 0, 0, 0);
            const float4 iv = ivb[cur][sub];
            const float4 gt = gtb[cur][sub];
#pragma unroll
            for (int ni = 0; ni < 4; ++ni) {
                float e0 = __expf(fmaf(Sa[ni][0], iv.x, gt.x));
                float e1 = __expf(fmaf(Sa[ni][1], iv.y, gt.y));
                float e2 = __expf(fmaf(Sa[ni][2], iv.z, gt.z));
                float e3 = __expf(fmaf(Sa[ni][3], iv.w, gt.w));
                be[ni].h[sub * 2]     = __float22bfloat162_rn(make_float2(e0, e1));
                be[ni].h[sub * 2 + 1] = __float22bfloat162_rn(make_float2(e2, e3));
                l_acc[ni] += (e0 + e1) + (e2 + e3);
            }
        }
        // ---- PV from Va[cur] ----
#pragma unroll
        for (int ct = 0; ct < 8; ++ct)
#pragma unroll
            for (int ni = 0; ni < 4; ++ni)
                O[ct][ni] = __builtin_amdgcn_mfma_f32_16x16x32_bf16(Va[cur][ct], be[ni].v, O[ct][ni], 0, 0, 0);
    }

    // ---- lpart: reduce l_acc over quads (lanes with same l15 share q) ----
#pragma unroll
    for (int ni = 0; ni < 4; ++ni) {
        float lt = l_acc[ni];
        lt += __shfl_xor(lt, 16);
        lt += __shfl_xor(lt, 32);
        if (quad == 0)
            lpart[(ks * 8 + b) * 4096 + q0 + ni * 16 + l15] = lt;
    }
    // ---- O write: per (ct,ni,r), 16 lanes write 16 consecutive q (64B) ----
    float* Ob = Opart + (long)(ks * 8 + b) * 524288;
#pragma unroll
    for (int ct = 0; ct < 8; ++ct)
#pragma unroll
        for (int ni = 0; ni < 4; ++ni) {
            int c = ct * 16 + quad * 4;
            int q = q0 + ni * 16 + l15;
#pragma unroll
            for (int r = 0; r < 4; ++r)
                Ob[((long)(c + r) << 12) + q] = O[ct][ni][r];
        }
}

// ---------------- combiner: merge 4 split-K partials ----------------
__global__ __launch_bounds__(256) void combiner_k(
    const float* __restrict__ Opart, const float* __restrict__ lpart,
    const float* __restrict__ F, const float* __restrict__ cw,
    const float* __restrict__ cb, float* __restrict__ out)
{
    const int tid = threadIdx.x;
    const int q = blockIdx.x * 256 + tid;
    const int o0 = blockIdx.y << 4;
    const int b = blockIdx.z;
    float lsum = 0.f;
#pragma unroll
    for (int ks = 0; ks < 4; ++ks) lsum += lpart[(ks * 8 + b) * 4096 + q];
    float il = 1.0f / lsum;
    const float* Fb = F + (long)b * 524288 + q;
    float acc[16];
#pragma unroll
    for (int j = 0; j < 16; ++j) acc[j] = cb[o0 + j];
    for (int c = 0; c < 128; ++c) {
        float a = 0.f;
#pragma unroll
        for (int ks = 0; ks < 4; ++ks)
            a += Opart[(long)(ks * 8 + b) * 524288 + (long)c * 4096 + q];
        a *= il;
        float f = Fb[(long)c * 4096];
#pragma unroll
        for (int j = 0; j < 16; ++j) {
            acc[j] = fmaf(cw[(o0 + j) * 256 + c], a, acc[j]);
            acc[j] = fmaf(cw[(o0 + j) * 256 + 128 + c], f, acc[j]);
        }
    }
#pragma unroll
    for (int j = 0; j < 16; ++j)
        out[((long)(b * 128 + o0 + j) << 12) + q] = acc[j];
}

// =====================================================================================
extern "C" void kernel_launch(void* const* d_in, const int* in_sizes, int n_in,
                              void* d_out, int out_size, void* d_ws, size_t ws_size,
                              hipStream_t stream)
{
    const float* F     = (const float*)d_in[0];
    const float* imgs  = (const float*)d_in[1];
    const float* masks = (const float*)d_in[2];
    const float* gw1 = (const float*)d_in[3];  const float* gb1 = (const float*)d_in[4];
    const float* gw2 = (const float*)d_in[5];  const float* gb2 = (const float*)d_in[6];
    const float* gw3 = (const float*)d_in[7];  const float* gb3 = (const float*)d_in[8];
    const float* gw4 = (const float*)d_in[9];  const float* gb4 = (const float*)d_in[10];
    const float* gw5 = (const float*)d_in[11]; const float* gb5 = (const float*)d_in[12];
    const float* cw  = (const float*)d_in[13]; const float* cb  = (const float*)d_in[14];
    float* out = (float*)d_out;

    // ---- workspace layout (float offsets), ~150 MB ----
    float* W = (float*)d_ws;
    ushort_t* Xcl2h = (ushort_t*)(W);                 // [8][260][260][32] fp16 h
    ushort_t* Xcl4h = (ushort_t*)(W);                 // [8][130][130][128] fp16 h
    float*    Opart = W;                              // [4][8][128][4096] f32
    float*    lpart = W + 16777216;                   // [4][8][4096]
    ushort_t* Xcl3h = (ushort_t*)(W + 17305600);      // [8][132][132][64] fp16 h
    ushort_t* Fo16  = (ushort_t*)(W + 17305600);      // [8][128][4096] bf16 (after conv3)
    float*    s4   = W + 26226688;                    // [8][256][64][64] f32
    ushort_t* Ft16 = (ushort_t*)(W + 30420992);       // [8][4096][128] bf16 (after conv5)
    ushort_t* W2h = (ushort_t*)(W + 34615296);
    ushort_t* W2l = (ushort_t*)(W + 34640896);
    ushort_t* W3h = (ushort_t*)(W + 34666496);
    ushort_t* W3l = (ushort_t*)(W + 34768896);
    ushort_t* W4h = (ushort_t*)(W + 34871296);
    ushort_t* W4l = (ushort_t*)(W + 35018752);
    float* gate = W + 35166208;
    float* invn = W + 35198976;
    ushort_t* Xinh = (ushort_t*)(W + 35231744);       // [8][262][262][4] fp16 h + slack
    ushort_t* W1h  = (ushort_t*)(W + 37428416);       // [7][32][32] fp16
    ushort_t* W1l  = (ushort_t*)(W + 37432000);

    // ---- weight transforms + conv1 input prep ----
    transform_w_k<<<dim3(200),  256, 0, stream>>>(gw2, W2h, W2l, 64, 32, 25);
    transform_w_k<<<dim3(800),  256, 0, stream>>>(gw3, W3h, W3l, 128, 64, 25);
    transform_w_k<<<dim3(1152), 256, 0, stream>>>(gw4, W4h, W4l, 256, 128, 9);
    transform_w1_k<<<dim3(28), 256, 0, stream>>>(gw1, W1h, W1l);
    prep_in_k<<<dim3(262, 8), 256, 0, stream>>>(imgs, masks, Xinh);

    // ---- conv stack (2-term split: weights h+l, activations h only) ----
    conv1_mfma_k<<<dim3(4, 256, 8), 256, 0, stream>>>(Xinh, W1h, W1l, gb1, Xcl2h);
    pad_cl_k<<<dim3(260, 8), 256, 0, stream>>>(Xcl2h, 260, 260, 2, 32, 256, 256);
    conv_mfma_k<5, 2, 32, 32, 64, 128, true><<<dim3(1, 128, 8), 256, 0, stream>>>(
        Xcl2h, W2h, W2l, gb2, 260, 260, 64, Xcl3h, 132, 132, 2, nullptr);
    pad_cl_k<<<dim3(132, 8), 256, 0, stream>>>(Xcl3h, 132, 132, 2, 64, 128, 128);
    conv_mfma_k<5, 1, 64, 32, 64, 128, true><<<dim3(1, 128, 16), 256, 0, stream>>>(
        Xcl3h, W3h, W3l, gb3, 132, 132, 128, Xcl4h, 130, 130, 1, nullptr);
    pad_cl_k<<<dim3(130, 8), 256, 0, stream>>>(Xcl4h, 130, 130, 1, 128, 128, 128);
    conv_mfma_k<3, 2, 128, 32, 128, 64, false><<<dim3(1, 64, 16), 256, 0, stream>>>(
        Xcl4h, W4h, W4l, gb4, 130, 130, 256, nullptr, 0, 0, 0, s4);
    conv5_gate_k<<<dim3(64, 8), 256, 0, stream>>>(s4, gw5, gb5, gate);

    // ---- attention ----
    invn_k<<<dim3(16, 8), 256, 0, stream>>>(F, invn);
    prep_bf16_k<<<dim3(64, 8), 256, 0, stream>>>(F, Fo16, Ft16);
    flash_attn_k<<<dim3(8, 256, 1), 64, 0, stream>>>(Ft16, Fo16, invn, gate, Opart, lpart);
    combiner_k<<<dim3(16, 8, 8), 256, 0, stream>>>(Opart, lpart, F, cw, cb, out);
}